// Round 6
// baseline (813.058 us; speedup 1.0000x reference)
//
#include <hip/hip_runtime.h>
#include <stdint.h>

#define NNODES 20000
#define NEDGES 160000
#define NPAD   20096   // 157 * 128

typedef float f32x4 __attribute__((ext_vector_type(4)));
typedef float f32x2 __attribute__((ext_vector_type(2)));
typedef short s16x8 __attribute__((ext_vector_type(8)));
typedef unsigned int u32x4 __attribute__((ext_vector_type(4)));
typedef _Float16 h16x2 __attribute__((ext_vector_type(2)));

__device__ __forceinline__ float b2f(unsigned short b) {
    unsigned int u = ((unsigned int)b) << 16;
    return __builtin_bit_cast(float, u);
}
__device__ __forceinline__ unsigned short f2b(float f) {
    unsigned int u = __builtin_bit_cast(unsigned int, f);
    unsigned int r = (u + 0x7FFFu + ((u >> 16) & 1u)) >> 16;
    return (unsigned short)r;
}
// unpack 2 bf16 (packed in a dword) -> float2
__device__ __forceinline__ f32x2 unpack2(unsigned int u) {
    f32x2 r;
    r.x = __builtin_bit_cast(float, u << 16);
    r.y = __builtin_bit_cast(float, u & 0xFFFF0000u);
    return r;
}
// pack two fp32 -> fp16 pair in a dword
__device__ __forceinline__ unsigned int packh2(float a, float b) {
    h16x2 h = { (_Float16)a, (_Float16)b };
    return __builtin_bit_cast(unsigned int, h);
}
// fp16-pair dot with fp32 accumulate: one v_dot2_f32_f16
__device__ __forceinline__ float dot2h(unsigned int a, unsigned int b, float c) {
#if __has_builtin(__builtin_amdgcn_fdot2)
    return __builtin_amdgcn_fdot2(__builtin_bit_cast(h16x2, a),
                                  __builtin_bit_cast(h16x2, b), c, false);
#else
    float d;
    asm("v_dot2_f32_f16 %0, %1, %2, %3" : "=v"(d) : "v"(a), "v"(b), "v"(c));
    return d;
#endif
}

// ---- GEMM: C[M,N] = A[M,K](bf16) @ BT[N,K]^T(bf16); C fp32 or bf16 ----
// BK=64 (halves barrier count vs BK=32) + XOR bank-conflict swizzle:
// LDS rows are 128B; un-swizzled, lanes 0-15 of a ds_read_b128 all hit the same
// bank pair (8-way conflict). Swizzle: LDS 16B-slot s of row r holds global
// chunk s^(r&7) -- applied by pre-swizzling the GLOBAL source chunk (linear
// global_load_lds dest, rule: both-sides-or-neither), and XOR-ing on the read.
// K must be a multiple of 64 (all call sites: 512/768/256).
__global__ __launch_bounds__(256) void gemm_bt_kernel(
    const unsigned short* __restrict__ A,
    const unsigned short* __restrict__ BT,
    float* __restrict__ Cf,
    unsigned short* __restrict__ Cb,
    int M, int N, int K,
    const float* __restrict__ bias)
{
    __shared__ unsigned short As[128 * 64];
    __shared__ unsigned short Bs[128 * 64];
    const int tid  = threadIdx.x;
    const int wid  = tid >> 6;
    const int lane = tid & 63;
    const int bm = blockIdx.x * 128;
    const int bn = blockIdx.y * 128;
    const int wm = (wid & 1) * 64;
    const int wn = (wid >> 1) * 64;

    f32x4 acc[4][4];
#pragma unroll
    for (int i = 0; i < 4; i++)
#pragma unroll
        for (int j = 0; j < 4; j++) acc[i][j] = {0.f, 0.f, 0.f, 0.f};

    for (int k0 = 0; k0 < K; k0 += 64) {
#pragma unroll
        for (int r = 0; r < 4; r++) {
            int flat = r * 256 + tid;       // 0..1023
            int row  = flat >> 3;           // 128 rows
            int part = flat & 7;            // 8 x 16B chunks per row
            int pg   = part ^ (row & 7);    // pre-swizzled global chunk
            const unsigned short* ga = A  + (size_t)(bm + row) * K + k0 + pg * 8;
            const unsigned short* gb = BT + (size_t)(bn + row) * K + k0 + pg * 8;
            __builtin_amdgcn_global_load_lds(
                (const __attribute__((address_space(1))) unsigned int*)ga,
                (__attribute__((address_space(3))) unsigned int*)&As[flat * 8], 16, 0, 0);
            __builtin_amdgcn_global_load_lds(
                (const __attribute__((address_space(1))) unsigned int*)gb,
                (__attribute__((address_space(3))) unsigned int*)&Bs[flat * 8], 16, 0, 0);
        }
        __syncthreads();

        const int kq8 = lane >> 4;     // 0..3: which 8-short chunk within 32
        const int rl  = lane & 15;
#pragma unroll
        for (int kk = 0; kk < 2; kk++) {
            s16x8 af[4], bfr[4];
#pragma unroll
            for (int mi = 0; mi < 4; mi++) {
                int row = wm + mi * 16 + rl;
                int slot = (kk * 4 + kq8) ^ (row & 7);
                af[mi] = *(const s16x8*)&As[row * 64 + slot * 8];
            }
#pragma unroll
            for (int ni = 0; ni < 4; ni++) {
                int row = wn + ni * 16 + rl;
                int slot = (kk * 4 + kq8) ^ (row & 7);
                bfr[ni] = *(const s16x8*)&Bs[row * 64 + slot * 8];
            }
#pragma unroll
            for (int mi = 0; mi < 4; mi++)
#pragma unroll
                for (int ni = 0; ni < 4; ni++)
                    acc[mi][ni] = __builtin_amdgcn_mfma_f32_16x16x32_bf16(
                        af[mi], bfr[ni], acc[mi][ni], 0, 0, 0);
        }
        __syncthreads();
    }

    const int cl = lane & 15;
    const int rq = (lane >> 4) * 4;
#pragma unroll
    for (int mi = 0; mi < 4; mi++)
#pragma unroll
        for (int ni = 0; ni < 4; ni++)
#pragma unroll
            for (int r = 0; r < 4; r++) {
                int row = bm + wm + mi * 16 + rq + r;
                int col = bn + wn + ni * 16 + cl;
                float v = acc[mi][ni][r];
                if (Cb) {
                    if (bias) v = fmaxf(v + bias[col], 0.f);
                    Cb[(size_t)row * N + col] = f2b(v);
                } else {
                    Cf[(size_t)row * N + col] = v;
                }
            }
}

// ---------------- CSR build ----------------
__global__ void count_kernel(const int* __restrict__ ei, int* __restrict__ counts) {
    int e = blockIdx.x * blockDim.x + threadIdx.x;
    if (e < NEDGES) atomicAdd(&counts[ei[NEDGES + e]], 1);
}

__global__ __launch_bounds__(1024) void scan_kernel(const int* __restrict__ counts,
                                                    int* __restrict__ row_ptr)
{
    __shared__ int sdata[1024];
    const int t = threadIdx.x;
    int vals[20];
    const int base = t * 20;
    int lsum = 0;
#pragma unroll
    for (int j = 0; j < 20; j++) {
        int idx = base + j;
        int v = (idx < NNODES) ? counts[idx] : 0;
        vals[j] = v; lsum += v;
    }
    sdata[t] = lsum;
    __syncthreads();
    for (int off = 1; off < 1024; off <<= 1) {
        int v = (t >= off) ? sdata[t - off] : 0;
        __syncthreads();
        sdata[t] += v;
        __syncthreads();
    }
    int run = sdata[t] - lsum;
#pragma unroll
    for (int j = 0; j < 20; j++) {
        int idx = base + j;
        if (idx < NNODES) row_ptr[idx] = run;
        run += vals[j];
    }
    if (t == 1023) row_ptr[NNODES] = sdata[1023];
}

__global__ void fill_kernel(const int* __restrict__ ei,
                            const int* __restrict__ row_ptr,
                            int* __restrict__ cursor,
                            int* __restrict__ csr_src,
                            int* __restrict__ csr_eid)
{
    int e = blockIdx.x * blockDim.x + threadIdx.x;
    if (e >= NEDGES) return;
    int dst = ei[NEDGES + e];
    int p = row_ptr[dst] + atomicAdd(&cursor[dst], 1);
    csr_src[p] = ei[e];
    csr_eid[p] = e;
}

__global__ void dinv_kernel(const int* __restrict__ row_ptr, float* __restrict__ dinv) {
    int i = blockIdx.x * blockDim.x + threadIdx.x;
    if (i < NNODES) {
        int deg = row_ptr[i + 1] - row_ptr[i] + 1;   // + self loop
        dinv[i] = rsqrtf((float)deg);
    }
}

// ---------------- packing ----------------
__global__ void pad_copy_kernel(const float* __restrict__ src,
                                unsigned short* __restrict__ dst,
                                int valid_rows, int cols, long total)
{
    long idx = (long)blockIdx.x * blockDim.x + threadIdx.x;
    if (idx >= total) return;
    int n = (int)(idx / cols);
    dst[idx] = (n < valid_rows) ? f2b(src[idx]) : (unsigned short)0;
}

// Interleaved P column layout (groups of 4 columns per channel pair):
//   cols [0,1024):   group cp: [f_dst[2cp], f_dst[2cp+1], s_dst[2cp], s_dst[2cp+1]]
//   cols [1024,2048): same for src projections
// -> per-edge gather reads ONE dwordx2.
__global__ void pack_cgw_kernel(const float* __restrict__ Wf,
                                const float* __restrict__ Ws,
                                unsigned short* __restrict__ out)
{
    int idx = blockIdx.x * blockDim.x + threadIdx.x;
    if (idx >= 2048 * 512) return;
    int j = idx >> 9;          // output column (wpack row) 0..2047
    int k = idx & 511;         // K index
    int half = (j >= 1024);    // 0 = dst block, 1 = src block
    int jj = j & 1023;
    int c  = (jj >> 2) * 2 + (jj & 1);   // channel
    int fs = (jj >> 1) & 1;              // 0 = f, 1 = s
    const float* W = fs ? Ws : Wf;
    float v = W[(size_t)(half ? 512 + k : k) * 512 + c];
    out[idx] = f2b(v);
}

__global__ void pack_t_kernel(const float* __restrict__ W,
                              unsigned short* __restrict__ WT,
                              int K, int Nout)
{
    long idx = (long)blockIdx.x * blockDim.x + threadIdx.x;
    if (idx >= (long)K * Nout) return;
    int j = (int)(idx / K);
    int k = (int)(idx % K);
    WT[idx] = f2b(W[(size_t)k * Nout + j]);
}

// W_e table in fp16 pairs for the gather's dot2 path:
// out dword idx = k*1024 + c2*4 + q, q: 0=f@c0 1=f@c1 2=s@c0 3=s@c1 (c0=2*c2)
// value = (W[1024+2k][c], W[1024+2k+1][c]) as 2 x fp16
__global__ void pack_we_kernel(const float* __restrict__ Wf,
                               const float* __restrict__ Ws,
                               unsigned int* __restrict__ out)
{
    int idx = blockIdx.x * blockDim.x + threadIdx.x;
    if (idx >= 8192) return;
    int q  = idx & 3;
    int c2 = (idx >> 2) & 255;
    int k  = idx >> 10;
    const float* W = (q >> 1) ? Ws : Wf;
    int c = c2 * 2 + (q & 1);
    float v0 = W[(size_t)(1024 + 2 * k) * 512 + c];
    float v1 = W[(size_t)(1024 + 2 * k + 1) * 512 + c];
    out[idx] = packh2(v0, v1);
}

// edge attrs as fp16 pairs in CSR order: eapk[i][j] = (ea[eid][2j], ea[eid][2j+1])
__global__ void pack_ea_kernel(const int* __restrict__ csr_eid,
                               const float* __restrict__ ea,
                               unsigned int* __restrict__ out)
{
    int idx = blockIdx.x * blockDim.x + threadIdx.x;
    if (idx >= NEDGES * 8) return;
    int i = idx >> 3;
    int j = idx & 7;
    int eid = csr_eid[i];
    out[idx] = packh2(ea[(size_t)eid * 16 + 2 * j], ea[(size_t)eid * 16 + 2 * j + 1]);
}

// ---------------- CGConv gather (fp16 dot2, depth-3 pipeline) ----------------
// R3-style loop control (plain row_ptr loads; R4's readfirstlane scalarization
// measured WORSE). csr_src still readfirstlane'd so the P-gather base is scalar.
// Depth-3 named register sets: loads issued 3 edges ahead of use.
#define CG_NPB 4

#define CG_LOADE(q_, a0_, a1_, idx) do {                                       \
    int sx_ = __builtin_amdgcn_readfirstlane(csr_src[idx]);                    \
    q_  = *(const uint2*)(P + (size_t)sx_ * 2048 + 1024 + c0 * 2);             \
    a0_ = eapk[(size_t)(idx) * 2];                                             \
    a1_ = eapk[(size_t)(idx) * 2 + 1];                                         \
} while (0)

#define CG_COMP(q_, a0_, a1_) do {                                             \
    float f0 = baseF.x, f1 = baseF.y, s0 = baseS.x, s1 = baseS.y;              \
    _Pragma("unroll")                                                          \
    for (int k = 0; k < 4; k++) {                                              \
        f0 = dot2h(a0_[k], w[k][0], f0);                                       \
        f1 = dot2h(a0_[k], w[k][1], f1);                                       \
        s0 = dot2h(a0_[k], w[k][2], s0);                                       \
        s1 = dot2h(a0_[k], w[k][3], s1);                                       \
    }                                                                          \
    _Pragma("unroll")                                                          \
    for (int k = 0; k < 4; k++) {                                              \
        f0 = dot2h(a1_[k], w[4 + k][0], f0);                                   \
        f1 = dot2h(a1_[k], w[4 + k][1], f1);                                   \
        s0 = dot2h(a1_[k], w[4 + k][2], s0);                                   \
        s1 = dot2h(a1_[k], w[4 + k][3], s1);                                   \
    }                                                                          \
    f32x2 pf = unpack2(q_.x);                                                  \
    f32x2 ps = unpack2(q_.y);                                                  \
    f0 += pf.x; f1 += pf.y; s0 += ps.x; s1 += ps.y;                            \
    float sp0 = __logf(1.f + __expf(s0));                                      \
    float sp1 = __logf(1.f + __expf(s1));                                      \
    float sg0 = __builtin_amdgcn_rcpf(1.f + __expf(-f0));                      \
    float sg1 = __builtin_amdgcn_rcpf(1.f + __expf(-f1));                      \
    acc.x = fmaf(sp0, sg0, acc.x);                                             \
    acc.y = fmaf(sp1, sg1, acc.y);                                             \
} while (0)

__global__ __launch_bounds__(256, 1) void cg_gather_kernel(
    const unsigned short* __restrict__ P,
    const int* __restrict__ row_ptr,
    const int* __restrict__ csr_src,
    const u32x4* __restrict__ wE,     // [8][256] fp16-pair weight table
    const u32x4* __restrict__ eapk,   // [NEDGES][2] fp16-pair attrs, CSR order
    const float* __restrict__ bfv,
    const float* __restrict__ bsv,
    const float* __restrict__ g,
    const float* __restrict__ be,
    const float* __restrict__ xresf,          // fp32 [NNODES,512] or null
    const unsigned short* __restrict__ xresb, // bf16 [NPAD,512] or null
    unsigned short* __restrict__ hout)
{
    const int tid = threadIdx.x;
    const int c0  = tid * 2;
    const int nbase = blockIdx.x * CG_NPB;

    u32x4 w[8];
#pragma unroll
    for (int k = 0; k < 8; k++) w[k] = wE[k * 256 + tid];

    const f32x2 bfx = *(const f32x2*)&bfv[c0];
    const f32x2 bsx = *(const f32x2*)&bsv[c0];
    const f32x2 gv  = *(const f32x2*)&g[c0];
    const f32x2 bev = *(const f32x2*)&be[c0];
    const float rs = rsqrtf(1.f + 1e-5f);

    for (int n = nbase; n < nbase + CG_NPB; n++) {
        if (n >= NNODES) {
            *(unsigned int*)&hout[(size_t)n * 512 + c0] = 0;
            continue;
        }
        const unsigned short* Pd = P + (size_t)n * 2048;
        const uint2 qb = *(const uint2*)(Pd + c0 * 2);
        const f32x2 baseF = unpack2(qb.x) + bfx;
        const f32x2 baseS = unpack2(qb.y) + bsx;

        f32x2 acc = {0.f, 0.f};
        const int i0 = row_ptr[n], i1 = row_ptr[n + 1];

        if (i0 < i1) {
            uint2 qA = {}, qB = {}, qC = {};
            u32x4 aA0 = {}, aA1 = {}, aB0 = {}, aB1 = {}, aC0 = {}, aC1 = {};
            CG_LOADE(qA, aA0, aA1, i0);
            if (i0 + 1 < i1) CG_LOADE(qB, aB0, aB1, i0 + 1);
            if (i0 + 2 < i1) CG_LOADE(qC, aC0, aC1, i0 + 2);
            int i = i0;
            while (true) {
                CG_COMP(qA, aA0, aA1);
                if (i + 3 < i1) CG_LOADE(qA, aA0, aA1, i + 3);
                if (++i >= i1) break;
                CG_COMP(qB, aB0, aB1);
                if (i + 3 < i1) CG_LOADE(qB, aB0, aB1, i + 3);
                if (++i >= i1) break;
                CG_COMP(qC, aC0, aC1);
                if (i + 3 < i1) CG_LOADE(qC, aC0, aC1, i + 3);
                if (++i >= i1) break;
            }
        }

        // fused BN(eval) + residual + ReLU
        f32x2 res;
        if (xresf) {
            res = *(const f32x2*)&xresf[(size_t)n * 512 + c0];
        } else {
            res = unpack2(*(const unsigned int*)&xresb[(size_t)n * 512 + c0]);
        }
        float v0 = fmaxf(acc.x * (gv.x * rs) + bev.x + res.x, 0.f);
        float v1 = fmaxf(acc.y * (gv.y * rs) + bev.y + res.y, 0.f);
        unsigned int packed = (unsigned int)f2b(v0) | ((unsigned int)f2b(v1) << 16);
        *(unsigned int*)&hout[(size_t)n * 512 + c0] = packed;
    }
}

// ---------------- GCN gather (1 wave per node, 4 ch/thread, depth-3) ----------------
__global__ __launch_bounds__(256) void gcn_gather_kernel(
    const unsigned short* __restrict__ pre,   // bf16 [NPAD,256]
    const int* __restrict__ row_ptr,
    const int* __restrict__ csr_src,
    const float* __restrict__ dinv,
    const float* __restrict__ b,
    unsigned short* __restrict__ hout,  // bf16 [NPAD,256]
    float* __restrict__ doutf)          // fp32 [NNODES,256] or null
{
    const int tid  = threadIdx.x;
    const int lane = tid & 63;
    const int n = blockIdx.x * 4 + (tid >> 6);   // one wave per node
    const int c = lane * 4;                      // 4 channels per thread
    if (n >= NNODES) {
        if (n < NPAD) { uint2 z = {0u, 0u}; *(uint2*)&hout[(size_t)n * 256 + c] = z; }
        return;
    }
    const float din = dinv[n];
    f32x4 acc = {0.f, 0.f, 0.f, 0.f};
    const int i0 = row_ptr[n], i1 = row_ptr[n + 1];

#define GCN_LOADE(dv_, pv_, idx) do {                                          \
    int sx_ = __builtin_amdgcn_readfirstlane(csr_src[idx]);                    \
    dv_ = dinv[sx_];                                                           \
    pv_ = *(const uint2*)&pre[(size_t)sx_ * 256 + c];                          \
} while (0)

#define GCN_COMP(dv_, pv_) do {                                                \
    f32x2 p0 = unpack2(pv_.x);                                                 \
    f32x2 p1 = unpack2(pv_.y);                                                 \
    acc.x = fmaf(dv_, p0.x, acc.x);                                            \
    acc.y = fmaf(dv_, p0.y, acc.y);                                            \
    acc.z = fmaf(dv_, p1.x, acc.z);                                            \
    acc.w = fmaf(dv_, p1.y, acc.w);                                            \
} while (0)

    if (i0 < i1) {
        float dvA = 0.f, dvB = 0.f, dvC = 0.f;
        uint2 pvA = {}, pvB = {}, pvC = {};
        GCN_LOADE(dvA, pvA, i0);
        if (i0 + 1 < i1) GCN_LOADE(dvB, pvB, i0 + 1);
        if (i0 + 2 < i1) GCN_LOADE(dvC, pvC, i0 + 2);
        int i = i0;
        while (true) {
            GCN_COMP(dvA, pvA);
            if (i + 3 < i1) GCN_LOADE(dvA, pvA, i + 3);
            if (++i >= i1) break;
            GCN_COMP(dvB, pvB);
            if (i + 3 < i1) GCN_LOADE(dvB, pvB, i + 3);
            if (++i >= i1) break;
            GCN_COMP(dvC, pvC);
            if (i + 3 < i1) GCN_LOADE(dvC, pvC, i + 3);
            if (++i >= i1) break;
        }
    }
    uint2 sv = *(const uint2*)&pre[(size_t)n * 256 + c];
    f32x2 s0 = unpack2(sv.x);
    f32x2 s1 = unpack2(sv.y);
    const f32x4 bv = *(const f32x4*)&b[c];
    const float d2 = din * din;
    float v0 = fmaxf(fmaf(acc.x, din, d2 * s0.x) + bv.x, 0.f);
    float v1 = fmaxf(fmaf(acc.y, din, d2 * s0.y) + bv.y, 0.f);
    float v2 = fmaxf(fmaf(acc.z, din, d2 * s1.x) + bv.z, 0.f);
    float v3 = fmaxf(fmaf(acc.w, din, d2 * s1.y) + bv.w, 0.f);
    uint2 o;
    o.x = (unsigned int)f2b(v0) | ((unsigned int)f2b(v1) << 16);
    o.y = (unsigned int)f2b(v2) | ((unsigned int)f2b(v3) << 16);
    *(uint2*)&hout[(size_t)n * 256 + c] = o;
    if (doutf) {
        f32x4 vv = {v0, v1, v2, v3};
        *(f32x4*)&doutf[(size_t)n * 256 + c] = vv;
    }
}

// ---------------- MLP ----------------
__global__ void build_zc_kernel(const unsigned short* __restrict__ h4,
                                const float* __restrict__ goal,
                                unsigned short* __restrict__ zc)
{
    long idx = (long)blockIdx.x * blockDim.x + threadIdx.x;
    if (idx >= (long)NPAD * 768) return;
    int n = (int)(idx / 768);
    int c = (int)(idx % 768);
    unsigned short v = 0;
    if (n < NNODES)
        v = (c < 256) ? h4[(size_t)n * 256 + c]
                      : f2b(goal[(size_t)n * 512 + (c - 256)]);
    zc[idx] = v;
}

__global__ __launch_bounds__(256) void final_dot_kernel(
    const unsigned short* __restrict__ t,
    const float* __restrict__ Wd2,
    const float* __restrict__ bd2,
    float* __restrict__ pred)
{
    const int lane = threadIdx.x & 63;
    const int wid  = threadIdx.x >> 6;
    float w[8];
#pragma unroll
    for (int i = 0; i < 8; i++) w[i] = Wd2[lane * 8 + i];
    const float bd = bd2[0];
    for (int n = blockIdx.x * 4 + wid; n < NNODES; n += gridDim.x * 4) {
        const unsigned short* tp = t + (size_t)n * 512 + lane * 8;
        float s = 0.f;
#pragma unroll
        for (int i = 0; i < 8; i++) s = fmaf(b2f(tp[i]), w[i], s);
#pragma unroll
        for (int off = 32; off; off >>= 1) s += __shfl_xor(s, off, 64);
        if (lane == 0) pred[n] = s + bd;
    }
}

// ---------------- launcher ----------------
extern "C" void kernel_launch(void* const* d_in, const int* in_sizes, int n_in,
                              void* d_out, int out_size, void* d_ws, size_t ws_size,
                              hipStream_t stream)
{
    (void)in_sizes; (void)n_in; (void)out_size; (void)ws_size;
    const float* x    = (const float*)d_in[0];
    const int*   ei   = (const int*)d_in[1];
    const float* ea   = (const float*)d_in[2];
    const float* goal = (const float*)d_in[3];
    const float* Wf1  = (const float*)d_in[4];
    const float* bf1  = (const float*)d_in[5];
    const float* Ws1  = (const float*)d_in[6];
    const float* bs1  = (const float*)d_in[7];
    const float* g1   = (const float*)d_in[8];
    const float* be1  = (const float*)d_in[9];
    const float* Wf2  = (const float*)d_in[10];
    const float* bf2  = (const float*)d_in[11];
    const float* Ws2  = (const float*)d_in[12];
    const float* bs2  = (const float*)d_in[13];
    const float* g2   = (const float*)d_in[14];
    const float* be2  = (const float*)d_in[15];
    const float* W3   = (const float*)d_in[16];
    const float* b3   = (const float*)d_in[17];
    const float* W4   = (const float*)d_in[18];
    const float* b4   = (const float*)d_in[19];
    const float* Wd1  = (const float*)d_in[20];
    const float* bd1  = (const float*)d_in[21];
    const float* Wd2  = (const float*)d_in[22];
    const float* bd2  = (const float*)d_in[23];
    float* outp = (float*)d_out;   // fp32: [0..N) pred, [N..N+N*256) h

    char* ws = (char*)d_ws;
    size_t off = 0;
    auto alloc = [&](size_t bytes) -> char* {
        char* p = ws + off;
        off += (bytes + 255) & ~(size_t)255;
        return p;
    };
    unsigned short* P     = (unsigned short*)alloc((size_t)NPAD * 2048 * 2); // later zc + tb
    unsigned short* bufA  = (unsigned short*)alloc((size_t)NPAD * 512 * 2);  // xpad / h2 / h4
    unsigned short* bufB  = (unsigned short*)alloc((size_t)NPAD * 512 * 2);  // h1 / pre_b
    unsigned short* bufC  = (unsigned short*)alloc((size_t)NPAD * 512 * 2);  // h3
    unsigned short* wpack = (unsigned short*)alloc((size_t)2048 * 512 * 2);
    int*            counts  = (int*)alloc((size_t)NNODES * 4);
    int*            row_ptr = (int*)alloc((size_t)(NNODES + 1) * 4);
    int*            csr_src = (int*)alloc((size_t)NEDGES * 4);
    int*            csr_eid = (int*)alloc((size_t)NEDGES * 4);
    float*          dinv    = (float*)alloc((size_t)NNODES * 4);
    unsigned int*   wEbuf   = (unsigned int*)alloc((size_t)8192 * 4);
    unsigned int*   eapk    = (unsigned int*)alloc((size_t)NEDGES * 8 * 4);

    unsigned short* xpad  = bufA;
    unsigned short* h1    = bufB;
    unsigned short* h2    = bufA;
    unsigned short* pre_b = bufB;
    unsigned short* h3    = bufC;
    unsigned short* h4    = bufA;
    unsigned short* zc    = P;
    unsigned short* tb    = P + (size_t)NPAD * 1024;

    const int B = 256;

    // ---- CSR build (by destination) + dinv ----
    hipMemsetAsync(counts, 0, (size_t)NNODES * 4, stream);
    count_kernel<<<(NEDGES + B - 1) / B, B, 0, stream>>>(ei, counts);
    scan_kernel<<<1, 1024, 0, stream>>>(counts, row_ptr);
    hipMemsetAsync(counts, 0, (size_t)NNODES * 4, stream);
    fill_kernel<<<(NEDGES + B - 1) / B, B, 0, stream>>>(ei, row_ptr, counts, csr_src, csr_eid);
    dinv_kernel<<<(NNODES + B - 1) / B, B, 0, stream>>>(row_ptr, dinv);
    pack_ea_kernel<<<(NEDGES * 8 + B - 1) / B, B, 0, stream>>>(csr_eid, ea, eapk);

    {
        long tot = (long)NPAD * 512;
        pad_copy_kernel<<<(unsigned)((tot + B - 1) / B), B, 0, stream>>>(x, xpad, NNODES, 512, tot);
    }

    dim3 gBig(NPAD / 128, 2048 / 128);

    // ---- CGConv layer 1 ----
    pack_cgw_kernel<<<(2048 * 512 + B - 1) / B, B, 0, stream>>>(Wf1, Ws1, wpack);
    pack_we_kernel<<<(8192 + B - 1) / B, B, 0, stream>>>(Wf1, Ws1, wEbuf);
    gemm_bt_kernel<<<gBig, B, 0, stream>>>(xpad, wpack, nullptr, P, NPAD, 2048, 512, nullptr);
    cg_gather_kernel<<<NPAD / CG_NPB, B, 0, stream>>>(P, row_ptr, csr_src,
                                                      (const u32x4*)wEbuf, (const u32x4*)eapk,
                                                      bf1, bs1, g1, be1,
                                                      x, nullptr, h1);

    // ---- CGConv layer 2 ----
    pack_cgw_kernel<<<(2048 * 512 + B - 1) / B, B, 0, stream>>>(Wf2, Ws2, wpack);
    gemm_bt_kernel<<<gBig, B, 0, stream>>>(h1, wpack, nullptr, P, NPAD, 2048, 512, nullptr);
    pack_we_kernel<<<(8192 + B - 1) / B, B, 0, stream>>>(Wf2, Ws2, wEbuf);
    cg_gather_kernel<<<NPAD / CG_NPB, B, 0, stream>>>(P, row_ptr, csr_src,
                                                      (const u32x4*)wEbuf, (const u32x4*)eapk,
                                                      bf2, bs2, g2, be2,
                                                      nullptr, h1, h2);

    // ---- GCN layer 3 ----
    pack_t_kernel<<<(256 * 512 + B - 1) / B, B, 0, stream>>>(W3, wpack, 512, 256);
    gemm_bt_kernel<<<dim3(NPAD / 128, 2), B, 0, stream>>>(h2, wpack, nullptr, pre_b, NPAD, 256, 512, nullptr);
    gcn_gather_kernel<<<NPAD / 4, B, 0, stream>>>(pre_b, row_ptr, csr_src, dinv, b3, h3, (float*)nullptr);

    // ---- GCN layer 4 ----
    pack_t_kernel<<<(256 * 256 + B - 1) / B, B, 0, stream>>>(W4, wpack, 256, 256);
    gemm_bt_kernel<<<dim3(NPAD / 128, 2), B, 0, stream>>>(h3, wpack, nullptr, pre_b, NPAD, 256, 256, nullptr);
    gcn_gather_kernel<<<NPAD / 4, B, 0, stream>>>(pre_b, row_ptr, csr_src, dinv, b4, h4, outp + NNODES);

    // ---- distance MLP (bias+ReLU fused into GEMM epilogue) ----
    build_zc_kernel<<<(unsigned)(((long)NPAD * 768 + B - 1) / B), B, 0, stream>>>(h4, goal, zc);
    pack_t_kernel<<<(512 * 768 + B - 1) / B, B, 0, stream>>>(Wd1, wpack, 768, 512);
    gemm_bt_kernel<<<dim3(NPAD / 128, 4), B, 0, stream>>>(zc, wpack, nullptr, tb, NPAD, 512, 768, bd1);
    final_dot_kernel<<<512, B, 0, stream>>>(tb, Wd2, bd2, outp);
}

// Round 7
// 784.127 us; speedup vs baseline: 1.0369x; 1.0369x over previous
//
#include <hip/hip_runtime.h>
#include <stdint.h>

#define NNODES 20000
#define NEDGES 160000
#define NPAD   20096   // 157 * 128

typedef float f32x4 __attribute__((ext_vector_type(4)));
typedef float f32x2 __attribute__((ext_vector_type(2)));
typedef short s16x8 __attribute__((ext_vector_type(8)));
typedef unsigned int u32x4 __attribute__((ext_vector_type(4)));
typedef _Float16 h16x2 __attribute__((ext_vector_type(2)));

#define L2E 1.44269504088896340736f
#define LN2 0.6931471805599453f

__device__ __forceinline__ float b2f(unsigned short b) {
    unsigned int u = ((unsigned int)b) << 16;
    return __builtin_bit_cast(float, u);
}
__device__ __forceinline__ unsigned short f2b(float f) {
    unsigned int u = __builtin_bit_cast(unsigned int, f);
    unsigned int r = (u + 0x7FFFu + ((u >> 16) & 1u)) >> 16;
    return (unsigned short)r;
}
// unpack 2 bf16 (packed in a dword) -> float2
__device__ __forceinline__ f32x2 unpack2(unsigned int u) {
    f32x2 r;
    r.x = __builtin_bit_cast(float, u << 16);
    r.y = __builtin_bit_cast(float, u & 0xFFFF0000u);
    return r;
}
// pack two fp32 -> fp16 pair in a dword
__device__ __forceinline__ unsigned int packh2(float a, float b) {
    h16x2 h = { (_Float16)a, (_Float16)b };
    return __builtin_bit_cast(unsigned int, h);
}
// fp16-pair dot with fp32 accumulate: one v_dot2_f32_f16
__device__ __forceinline__ float dot2h(unsigned int a, unsigned int b, float c) {
#if __has_builtin(__builtin_amdgcn_fdot2)
    return __builtin_amdgcn_fdot2(__builtin_bit_cast(h16x2, a),
                                  __builtin_bit_cast(h16x2, b), c, false);
#else
    float d;
    asm("v_dot2_f32_f16 %0, %1, %2, %3" : "=v"(d) : "v"(a), "v"(b), "v"(c));
    return d;
#endif
}
__device__ __forceinline__ float exp2f_fast(float x) {
#if __has_builtin(__builtin_amdgcn_exp2f)
    return __builtin_amdgcn_exp2f(x);
#else
    return __builtin_exp2f(x);
#endif
}
__device__ __forceinline__ float log2f_fast(float x) {
#if __has_builtin(__builtin_amdgcn_logf)
    return __builtin_amdgcn_logf(x);
#else
    return __builtin_log2f(x);
#endif
}

// ---- GEMM: C[M,N] = A[M,K](bf16) @ BT[N,K]^T(bf16); C fp32 or bf16 ----
// BK=64 + XOR bank-conflict swizzle (pre-swizzled global chunk, swizzled read).
__global__ __launch_bounds__(256) void gemm_bt_kernel(
    const unsigned short* __restrict__ A,
    const unsigned short* __restrict__ BT,
    float* __restrict__ Cf,
    unsigned short* __restrict__ Cb,
    int M, int N, int K,
    const float* __restrict__ bias)
{
    __shared__ unsigned short As[128 * 64];
    __shared__ unsigned short Bs[128 * 64];
    const int tid  = threadIdx.x;
    const int wid  = tid >> 6;
    const int lane = tid & 63;
    const int bm = blockIdx.x * 128;
    const int bn = blockIdx.y * 128;
    const int wm = (wid & 1) * 64;
    const int wn = (wid >> 1) * 64;

    f32x4 acc[4][4];
#pragma unroll
    for (int i = 0; i < 4; i++)
#pragma unroll
        for (int j = 0; j < 4; j++) acc[i][j] = {0.f, 0.f, 0.f, 0.f};

    for (int k0 = 0; k0 < K; k0 += 64) {
#pragma unroll
        for (int r = 0; r < 4; r++) {
            int flat = r * 256 + tid;       // 0..1023
            int row  = flat >> 3;           // 128 rows
            int part = flat & 7;            // 8 x 16B chunks per row
            int pg   = part ^ (row & 7);    // pre-swizzled global chunk
            const unsigned short* ga = A  + (size_t)(bm + row) * K + k0 + pg * 8;
            const unsigned short* gb = BT + (size_t)(bn + row) * K + k0 + pg * 8;
            __builtin_amdgcn_global_load_lds(
                (const __attribute__((address_space(1))) unsigned int*)ga,
                (__attribute__((address_space(3))) unsigned int*)&As[flat * 8], 16, 0, 0);
            __builtin_amdgcn_global_load_lds(
                (const __attribute__((address_space(1))) unsigned int*)gb,
                (__attribute__((address_space(3))) unsigned int*)&Bs[flat * 8], 16, 0, 0);
        }
        __syncthreads();

        const int kq8 = lane >> 4;     // 0..3
        const int rl  = lane & 15;
#pragma unroll
        for (int kk = 0; kk < 2; kk++) {
            s16x8 af[4], bfr[4];
#pragma unroll
            for (int mi = 0; mi < 4; mi++) {
                int row = wm + mi * 16 + rl;
                int slot = (kk * 4 + kq8) ^ (row & 7);
                af[mi] = *(const s16x8*)&As[row * 64 + slot * 8];
            }
#pragma unroll
            for (int ni = 0; ni < 4; ni++) {
                int row = wn + ni * 16 + rl;
                int slot = (kk * 4 + kq8) ^ (row & 7);
                bfr[ni] = *(const s16x8*)&Bs[row * 64 + slot * 8];
            }
#pragma unroll
            for (int mi = 0; mi < 4; mi++)
#pragma unroll
                for (int ni = 0; ni < 4; ni++)
                    acc[mi][ni] = __builtin_amdgcn_mfma_f32_16x16x32_bf16(
                        af[mi], bfr[ni], acc[mi][ni], 0, 0, 0);
        }
        __syncthreads();
    }

    const int cl = lane & 15;
    const int rq = (lane >> 4) * 4;
#pragma unroll
    for (int mi = 0; mi < 4; mi++)
#pragma unroll
        for (int ni = 0; ni < 4; ni++)
#pragma unroll
            for (int r = 0; r < 4; r++) {
                int row = bm + wm + mi * 16 + rq + r;
                int col = bn + wn + ni * 16 + cl;
                float v = acc[mi][ni][r];
                if (Cb) {
                    if (bias) v = fmaxf(v + bias[col], 0.f);
                    Cb[(size_t)row * N + col] = f2b(v);
                } else {
                    Cf[(size_t)row * N + col] = v;
                }
            }
}

// ---------------- CSR build ----------------
__global__ void count_kernel(const int* __restrict__ ei, int* __restrict__ counts) {
    int e = blockIdx.x * blockDim.x + threadIdx.x;
    if (e < NEDGES) atomicAdd(&counts[ei[NEDGES + e]], 1);
}

__global__ __launch_bounds__(1024) void scan_kernel(const int* __restrict__ counts,
                                                    int* __restrict__ row_ptr)
{
    __shared__ int sdata[1024];
    const int t = threadIdx.x;
    int vals[20];
    const int base = t * 20;
    int lsum = 0;
#pragma unroll
    for (int j = 0; j < 20; j++) {
        int idx = base + j;
        int v = (idx < NNODES) ? counts[idx] : 0;
        vals[j] = v; lsum += v;
    }
    sdata[t] = lsum;
    __syncthreads();
    for (int off = 1; off < 1024; off <<= 1) {
        int v = (t >= off) ? sdata[t - off] : 0;
        __syncthreads();
        sdata[t] += v;
        __syncthreads();
    }
    int run = sdata[t] - lsum;
#pragma unroll
    for (int j = 0; j < 20; j++) {
        int idx = base + j;
        if (idx < NNODES) row_ptr[idx] = run;
        run += vals[j];
    }
    if (t == 1023) row_ptr[NNODES] = sdata[1023];
}

__global__ void fill_kernel(const int* __restrict__ ei,
                            const int* __restrict__ row_ptr,
                            int* __restrict__ cursor,
                            int* __restrict__ csr_src,
                            int* __restrict__ csr_eid)
{
    int e = blockIdx.x * blockDim.x + threadIdx.x;
    if (e >= NEDGES) return;
    int dst = ei[NEDGES + e];
    int p = row_ptr[dst] + atomicAdd(&cursor[dst], 1);
    csr_src[p] = ei[e];
    csr_eid[p] = e;
}

__global__ void dinv_kernel(const int* __restrict__ row_ptr, float* __restrict__ dinv) {
    int i = blockIdx.x * blockDim.x + threadIdx.x;
    if (i < NNODES) {
        int deg = row_ptr[i + 1] - row_ptr[i] + 1;   // + self loop
        dinv[i] = rsqrtf((float)deg);
    }
}

// ---------------- packing ----------------
__global__ void pad_copy_kernel(const float* __restrict__ src,
                                unsigned short* __restrict__ dst,
                                int valid_rows, int cols, long total)
{
    long idx = (long)blockIdx.x * blockDim.x + threadIdx.x;
    if (idx >= total) return;
    int n = (int)(idx / cols);
    dst[idx] = (n < valid_rows) ? f2b(src[idx]) : (unsigned short)0;
}

// Interleaved P column layout. ALL values pre-scaled by log2(e): the gather
// computes everything in base-2 (exp2/log2 raw HW ops); ln2 is folded into the
// BN gamma at the epilogue.
__global__ void pack_cgw_kernel(const float* __restrict__ Wf,
                                const float* __restrict__ Ws,
                                unsigned short* __restrict__ out)
{
    int idx = blockIdx.x * blockDim.x + threadIdx.x;
    if (idx >= 2048 * 512) return;
    int j = idx >> 9;          // output column (wpack row) 0..2047
    int k = idx & 511;         // K index
    int half = (j >= 1024);    // 0 = dst block, 1 = src block
    int jj = j & 1023;
    int c  = (jj >> 2) * 2 + (jj & 1);   // channel
    int fs = (jj >> 1) & 1;              // 0 = f, 1 = s
    const float* W = fs ? Ws : Wf;
    float v = W[(size_t)(half ? 512 + k : k) * 512 + c] * L2E;
    out[idx] = f2b(v);
}

__global__ void pack_t_kernel(const float* __restrict__ W,
                              unsigned short* __restrict__ WT,
                              int K, int Nout)
{
    long idx = (long)blockIdx.x * blockDim.x + threadIdx.x;
    if (idx >= (long)K * Nout) return;
    int j = (int)(idx / K);
    int k = (int)(idx % K);
    WT[idx] = f2b(W[(size_t)k * Nout + j]);
}

// W_e table, THREAD-MAJOR: dword idx = tid*32 + k*4 + q (128 B contiguous per
// thread -> 8 asm loads off one base with 13-bit offsets).
// q: 0=f@c0 1=f@c1 2=s@c0 3=s@c1 (c0 = 2*tid); value pre-scaled by log2(e).
__global__ void pack_we_kernel(const float* __restrict__ Wf,
                               const float* __restrict__ Ws,
                               unsigned int* __restrict__ out)
{
    int idx = blockIdx.x * blockDim.x + threadIdx.x;
    if (idx >= 8192) return;
    int tid = idx >> 5;
    int r   = idx & 31;
    int k   = r >> 2;
    int q   = r & 3;
    const float* W = (q >> 1) ? Ws : Wf;
    int c = tid * 2 + (q & 1);
    float v0 = W[(size_t)(1024 + 2 * k) * 512 + c] * L2E;
    float v1 = W[(size_t)(1024 + 2 * k + 1) * 512 + c] * L2E;
    out[idx] = packh2(v0, v1);
}

// edge attrs as fp16 pairs in CSR order: eapk[i][j] = (ea[eid][2j], ea[eid][2j+1])
__global__ void pack_ea_kernel(const int* __restrict__ csr_eid,
                               const float* __restrict__ ea,
                               unsigned int* __restrict__ out)
{
    int idx = blockIdx.x * blockDim.x + threadIdx.x;
    if (idx >= NEDGES * 8) return;
    int i = idx >> 3;
    int j = idx & 7;
    int eid = csr_eid[i];
    out[idx] = packh2(ea[(size_t)eid * 16 + 2 * j], ea[(size_t)eid * 16 + 2 * j + 1]);
}

// ---------------- CGConv gather ----------------
// R6 showed VGPR=36: the compiler was re-loading the 32-VGPR weight table from
// L1 EVERY EDGE (~8KB/wave-edge, ~67us/CU of L1 traffic + ~24 addr-VALU/edge).
// Fix: load weights via ONE asm volatile block (8x global_load_dwordx4 +
// s_waitcnt) -- volatile asm cannot be rematerialized, so the values stay
// register-resident. sched_barrier(0) after (guide rule #18).
// Loop: R3-proven depth-2 pipeline, NPB=4. Base-2 transcendentals (inputs
// pre-scaled by log2e in the pack kernels; ln2 folded into BN gamma).
#define CG_NPB 4

#define CG_LOADE(q_, a0_, a1_, idx) do {                                       \
    int sx_ = __builtin_amdgcn_readfirstlane(csr_src[idx]);                    \
    q_  = *(const uint2*)(P + (size_t)sx_ * 2048 + 1024 + c0 * 2);             \
    a0_ = eapk[(size_t)(idx) * 2];                                             \
    a1_ = eapk[(size_t)(idx) * 2 + 1];                                         \
} while (0)

#define CG_COMP(q_, a0_, a1_) do {                                             \
    float f0 = baseF.x, f1 = baseF.y, s0 = baseS.x, s1 = baseS.y;              \
    _Pragma("unroll")                                                          \
    for (int k = 0; k < 4; k++) {                                              \
        f0 = dot2h(a0_[k], w[k][0], f0);                                       \
        f1 = dot2h(a0_[k], w[k][1], f1);                                       \
        s0 = dot2h(a0_[k], w[k][2], s0);                                       \
        s1 = dot2h(a0_[k], w[k][3], s1);                                       \
    }                                                                          \
    _Pragma("unroll")                                                          \
    for (int k = 0; k < 4; k++) {                                              \
        f0 = dot2h(a1_[k], w[4 + k][0], f0);                                   \
        f1 = dot2h(a1_[k], w[4 + k][1], f1);                                   \
        s0 = dot2h(a1_[k], w[4 + k][2], s0);                                   \
        s1 = dot2h(a1_[k], w[4 + k][3], s1);                                   \
    }                                                                          \
    f32x2 pf = unpack2(q_.x);                                                  \
    f32x2 ps = unpack2(q_.y);                                                  \
    f0 += pf.x; f1 += pf.y; s0 += ps.x; s1 += ps.y;                            \
    float sp0 = log2f_fast(1.f + exp2f_fast(s0));                              \
    float sp1 = log2f_fast(1.f + exp2f_fast(s1));                              \
    float sg0 = __builtin_amdgcn_rcpf(1.f + exp2f_fast(-f0));                  \
    float sg1 = __builtin_amdgcn_rcpf(1.f + exp2f_fast(-f1));                  \
    acc.x = fmaf(sp0, sg0, acc.x);                                             \
    acc.y = fmaf(sp1, sg1, acc.y);                                             \
} while (0)

__global__ __launch_bounds__(256, 1) void cg_gather_kernel(
    const unsigned short* __restrict__ P,
    const int* __restrict__ row_ptr,
    const int* __restrict__ csr_src,
    const unsigned int* __restrict__ wE,   // [256][8][4] dwords, thread-major
    const u32x4* __restrict__ eapk,        // [NEDGES][2] fp16-pair attrs, CSR order
    const float* __restrict__ bfv,
    const float* __restrict__ bsv,
    const float* __restrict__ g,
    const float* __restrict__ be,
    const float* __restrict__ xresf,          // fp32 [NNODES,512] or null
    const unsigned short* __restrict__ xresb, // bf16 [NPAD,512] or null
    unsigned short* __restrict__ hout)
{
    const int tid = threadIdx.x;
    const int c0  = tid * 2;
    const int nbase = blockIdx.x * CG_NPB;

    // ---- register-resident weight table (asm volatile: cannot rematerialize)
    const unsigned int* wp = wE + (size_t)tid * 32;   // 128 B per thread
    u32x4 w0, w1, w2, w3, w4, w5, w6, w7;
    asm volatile(
        "global_load_dwordx4 %0, %8, off\n\t"
        "global_load_dwordx4 %1, %8, off offset:16\n\t"
        "global_load_dwordx4 %2, %8, off offset:32\n\t"
        "global_load_dwordx4 %3, %8, off offset:48\n\t"
        "global_load_dwordx4 %4, %8, off offset:64\n\t"
        "global_load_dwordx4 %5, %8, off offset:80\n\t"
        "global_load_dwordx4 %6, %8, off offset:96\n\t"
        "global_load_dwordx4 %7, %8, off offset:112\n\t"
        "s_waitcnt vmcnt(0)"
        : "=&v"(w0), "=&v"(w1), "=&v"(w2), "=&v"(w3),
          "=&v"(w4), "=&v"(w5), "=&v"(w6), "=&v"(w7)
        : "v"(wp));
    __builtin_amdgcn_sched_barrier(0);
    const u32x4 w[8] = {w0, w1, w2, w3, w4, w5, w6, w7};

    const f32x2 bfx = *(const f32x2*)&bfv[c0] * L2E;
    const f32x2 bsx = *(const f32x2*)&bsv[c0] * L2E;
    const f32x2 gv  = *(const f32x2*)&g[c0];
    const f32x2 bev = *(const f32x2*)&be[c0];
    const float rsl = rsqrtf(1.f + 1e-5f) * LN2;   // BN rs * ln2 (base-2 fold)

    for (int n = nbase; n < nbase + CG_NPB; n++) {
        if (n >= NNODES) {
            *(unsigned int*)&hout[(size_t)n * 512 + c0] = 0;
            continue;
        }
        const unsigned short* Pd = P + (size_t)n * 2048;
        const uint2 qb = *(const uint2*)(Pd + c0 * 2);
        const f32x2 baseF = unpack2(qb.x) + bfx;
        const f32x2 baseS = unpack2(qb.y) + bsx;

        f32x2 acc = {0.f, 0.f};
        const int i0 = row_ptr[n], i1 = row_ptr[n + 1];

        if (i0 < i1) {
            uint2 qA = {}, qB = {};
            u32x4 aA0 = {}, aA1 = {}, aB0 = {}, aB1 = {};
            CG_LOADE(qA, aA0, aA1, i0);
            if (i0 + 1 < i1) CG_LOADE(qB, aB0, aB1, i0 + 1);
            int i = i0;
            while (true) {
                CG_COMP(qA, aA0, aA1);
                if (i + 2 < i1) CG_LOADE(qA, aA0, aA1, i + 2);
                if (++i >= i1) break;
                CG_COMP(qB, aB0, aB1);
                if (i + 2 < i1) CG_LOADE(qB, aB0, aB1, i + 2);
                if (++i >= i1) break;
            }
        }

        // fused BN(eval) + residual + ReLU  (acc carries log2-form softplus)
        f32x2 res;
        if (xresf) {
            res = *(const f32x2*)&xresf[(size_t)n * 512 + c0];
        } else {
            res = unpack2(*(const unsigned int*)&xresb[(size_t)n * 512 + c0]);
        }
        float v0 = fmaxf(acc.x * (gv.x * rsl) + bev.x + res.x, 0.f);
        float v1 = fmaxf(acc.y * (gv.y * rsl) + bev.y + res.y, 0.f);
        unsigned int packed = (unsigned int)f2b(v0) | ((unsigned int)f2b(v1) << 16);
        *(unsigned int*)&hout[(size_t)n * 512 + c0] = packed;
    }
}

// ---------------- GCN gather (1 wave per node, 4 ch/thread, depth-3) ----------------
__global__ __launch_bounds__(256) void gcn_gather_kernel(
    const unsigned short* __restrict__ pre,   // bf16 [NPAD,256]
    const int* __restrict__ row_ptr,
    const int* __restrict__ csr_src,
    const float* __restrict__ dinv,
    const float* __restrict__ b,
    unsigned short* __restrict__ hout,  // bf16 [NPAD,256]
    float* __restrict__ doutf)          // fp32 [NNODES,256] or null
{
    const int tid  = threadIdx.x;
    const int lane = tid & 63;
    const int n = blockIdx.x * 4 + (tid >> 6);   // one wave per node
    const int c = lane * 4;                      // 4 channels per thread
    if (n >= NNODES) {
        if (n < NPAD) { uint2 z = {0u, 0u}; *(uint2*)&hout[(size_t)n * 256 + c] = z; }
        return;
    }
    const float din = dinv[n];
    f32x4 acc = {0.f, 0.f, 0.f, 0.f};
    const int i0 = row_ptr[n], i1 = row_ptr[n + 1];

#define GCN_LOADE(dv_, pv_, idx) do {                                          \
    int sx_ = __builtin_amdgcn_readfirstlane(csr_src[idx]);                    \
    dv_ = dinv[sx_];                                                           \
    pv_ = *(const uint2*)&pre[(size_t)sx_ * 256 + c];                          \
} while (0)

#define GCN_COMP(dv_, pv_) do {                                                \
    f32x2 p0 = unpack2(pv_.x);                                                 \
    f32x2 p1 = unpack2(pv_.y);                                                 \
    acc.x = fmaf(dv_, p0.x, acc.x);                                            \
    acc.y = fmaf(dv_, p0.y, acc.y);                                            \
    acc.z = fmaf(dv_, p1.x, acc.z);                                            \
    acc.w = fmaf(dv_, p1.y, acc.w);                                            \
} while (0)

    if (i0 < i1) {
        float dvA = 0.f, dvB = 0.f, dvC = 0.f;
        uint2 pvA = {}, pvB = {}, pvC = {};
        GCN_LOADE(dvA, pvA, i0);
        if (i0 + 1 < i1) GCN_LOADE(dvB, pvB, i0 + 1);
        if (i0 + 2 < i1) GCN_LOADE(dvC, pvC, i0 + 2);
        int i = i0;
        while (true) {
            GCN_COMP(dvA, pvA);
            if (i + 3 < i1) GCN_LOADE(dvA, pvA, i + 3);
            if (++i >= i1) break;
            GCN_COMP(dvB, pvB);
            if (i + 3 < i1) GCN_LOADE(dvB, pvB, i + 3);
            if (++i >= i1) break;
            GCN_COMP(dvC, pvC);
            if (i + 3 < i1) GCN_LOADE(dvC, pvC, i + 3);
            if (++i >= i1) break;
        }
    }
    uint2 sv = *(const uint2*)&pre[(size_t)n * 256 + c];
    f32x2 s0 = unpack2(sv.x);
    f32x2 s1 = unpack2(sv.y);
    const f32x4 bv = *(const f32x4*)&b[c];
    const float d2 = din * din;
    float v0 = fmaxf(fmaf(acc.x, din, d2 * s0.x) + bv.x, 0.f);
    float v1 = fmaxf(fmaf(acc.y, din, d2 * s0.y) + bv.y, 0.f);
    float v2 = fmaxf(fmaf(acc.z, din, d2 * s1.x) + bv.z, 0.f);
    float v3 = fmaxf(fmaf(acc.w, din, d2 * s1.y) + bv.w, 0.f);
    uint2 o;
    o.x = (unsigned int)f2b(v0) | ((unsigned int)f2b(v1) << 16);
    o.y = (unsigned int)f2b(v2) | ((unsigned int)f2b(v3) << 16);
    *(uint2*)&hout[(size_t)n * 256 + c] = o;
    if (doutf) {
        f32x4 vv = {v0, v1, v2, v3};
        *(f32x4*)&doutf[(size_t)n * 256 + c] = vv;
    }
}

// ---------------- MLP ----------------
__global__ void build_zc_kernel(const unsigned short* __restrict__ h4,
                                const float* __restrict__ goal,
                                unsigned short* __restrict__ zc)
{
    long idx = (long)blockIdx.x * blockDim.x + threadIdx.x;
    if (idx >= (long)NPAD * 768) return;
    int n = (int)(idx / 768);
    int c = (int)(idx % 768);
    unsigned short v = 0;
    if (n < NNODES)
        v = (c < 256) ? h4[(size_t)n * 256 + c]
                      : f2b(goal[(size_t)n * 512 + (c - 256)]);
    zc[idx] = v;
}

__global__ __launch_bounds__(256) void final_dot_kernel(
    const unsigned short* __restrict__ t,
    const float* __restrict__ Wd2,
    const float* __restrict__ bd2,
    float* __restrict__ pred)
{
    const int lane = threadIdx.x & 63;
    const int wid  = threadIdx.x >> 6;
    float w[8];
#pragma unroll
    for (int i = 0; i < 8; i++) w[i] = Wd2[lane * 8 + i];
    const float bd = bd2[0];
    for (int n = blockIdx.x * 4 + wid; n < NNODES; n += gridDim.x * 4) {
        const unsigned short* tp = t + (size_t)n * 512 + lane * 8;
        float s = 0.f;
#pragma unroll
        for (int i = 0; i < 8; i++) s = fmaf(b2f(tp[i]), w[i], s);
#pragma unroll
        for (int off = 32; off; off >>= 1) s += __shfl_xor(s, off, 64);
        if (lane == 0) pred[n] = s + bd;
    }
}

// ---------------- launcher ----------------
extern "C" void kernel_launch(void* const* d_in, const int* in_sizes, int n_in,
                              void* d_out, int out_size, void* d_ws, size_t ws_size,
                              hipStream_t stream)
{
    (void)in_sizes; (void)n_in; (void)out_size; (void)ws_size;
    const float* x    = (const float*)d_in[0];
    const int*   ei   = (const int*)d_in[1];
    const float* ea   = (const float*)d_in[2];
    const float* goal = (const float*)d_in[3];
    const float* Wf1  = (const float*)d_in[4];
    const float* bf1  = (const float*)d_in[5];
    const float* Ws1  = (const float*)d_in[6];
    const float* bs1  = (const float*)d_in[7];
    const float* g1   = (const float*)d_in[8];
    const float* be1  = (const float*)d_in[9];
    const float* Wf2  = (const float*)d_in[10];
    const float* bf2  = (const float*)d_in[11];
    const float* Ws2  = (const float*)d_in[12];
    const float* bs2  = (const float*)d_in[13];
    const float* g2   = (const float*)d_in[14];
    const float* be2  = (const float*)d_in[15];
    const float* W3   = (const float*)d_in[16];
    const float* b3   = (const float*)d_in[17];
    const float* W4   = (const float*)d_in[18];
    const float* b4   = (const float*)d_in[19];
    const float* Wd1  = (const float*)d_in[20];
    const float* bd1  = (const float*)d_in[21];
    const float* Wd2  = (const float*)d_in[22];
    const float* bd2  = (const float*)d_in[23];
    float* outp = (float*)d_out;   // fp32: [0..N) pred, [N..N+N*256) h

    char* ws = (char*)d_ws;
    size_t off = 0;
    auto alloc = [&](size_t bytes) -> char* {
        char* p = ws + off;
        off += (bytes + 255) & ~(size_t)255;
        return p;
    };
    unsigned short* P     = (unsigned short*)alloc((size_t)NPAD * 2048 * 2); // later zc + tb
    unsigned short* bufA  = (unsigned short*)alloc((size_t)NPAD * 512 * 2);  // xpad / h2 / h4
    unsigned short* bufB  = (unsigned short*)alloc((size_t)NPAD * 512 * 2);  // h1 / pre_b
    unsigned short* bufC  = (unsigned short*)alloc((size_t)NPAD * 512 * 2);  // h3
    unsigned short* wpack = (unsigned short*)alloc((size_t)2048 * 512 * 2);
    int*            counts  = (int*)alloc((size_t)NNODES * 4);
    int*            row_ptr = (int*)alloc((size_t)(NNODES + 1) * 4);
    int*            csr_src = (int*)alloc((size_t)NEDGES * 4);
    int*            csr_eid = (int*)alloc((size_t)NEDGES * 4);
    float*          dinv    = (float*)alloc((size_t)NNODES * 4);
    unsigned int*   wEbuf   = (unsigned int*)alloc((size_t)8192 * 4);
    unsigned int*   eapk    = (unsigned int*)alloc((size_t)NEDGES * 8 * 4);

    unsigned short* xpad  = bufA;
    unsigned short* h1    = bufB;
    unsigned short* h2    = bufA;
    unsigned short* pre_b = bufB;
    unsigned short* h3    = bufC;
    unsigned short* h4    = bufA;
    unsigned short* zc    = P;
    unsigned short* tb    = P + (size_t)NPAD * 1024;

    const int B = 256;

    // ---- CSR build (by destination) + dinv ----
    hipMemsetAsync(counts, 0, (size_t)NNODES * 4, stream);
    count_kernel<<<(NEDGES + B - 1) / B, B, 0, stream>>>(ei, counts);
    scan_kernel<<<1, 1024, 0, stream>>>(counts, row_ptr);
    hipMemsetAsync(counts, 0, (size_t)NNODES * 4, stream);
    fill_kernel<<<(NEDGES + B - 1) / B, B, 0, stream>>>(ei, row_ptr, counts, csr_src, csr_eid);
    dinv_kernel<<<(NNODES + B - 1) / B, B, 0, stream>>>(row_ptr, dinv);
    pack_ea_kernel<<<(NEDGES * 8 + B - 1) / B, B, 0, stream>>>(csr_eid, ea, eapk);

    {
        long tot = (long)NPAD * 512;
        pad_copy_kernel<<<(unsigned)((tot + B - 1) / B), B, 0, stream>>>(x, xpad, NNODES, 512, tot);
    }

    dim3 gBig(NPAD / 128, 2048 / 128);

    // ---- CGConv layer 1 ----
    pack_cgw_kernel<<<(2048 * 512 + B - 1) / B, B, 0, stream>>>(Wf1, Ws1, wpack);
    pack_we_kernel<<<(8192 + B - 1) / B, B, 0, stream>>>(Wf1, Ws1, wEbuf);
    gemm_bt_kernel<<<gBig, B, 0, stream>>>(xpad, wpack, nullptr, P, NPAD, 2048, 512, nullptr);
    cg_gather_kernel<<<NPAD / CG_NPB, B, 0, stream>>>(P, row_ptr, csr_src,
                                                      wEbuf, (const u32x4*)eapk,
                                                      bf1, bs1, g1, be1,
                                                      x, nullptr, h1);

    // ---- CGConv layer 2 ----
    pack_cgw_kernel<<<(2048 * 512 + B - 1) / B, B, 0, stream>>>(Wf2, Ws2, wpack);
    gemm_bt_kernel<<<gBig, B, 0, stream>>>(h1, wpack, nullptr, P, NPAD, 2048, 512, nullptr);
    pack_we_kernel<<<(8192 + B - 1) / B, B, 0, stream>>>(Wf2, Ws2, wEbuf);
    cg_gather_kernel<<<NPAD / CG_NPB, B, 0, stream>>>(P, row_ptr, csr_src,
                                                      wEbuf, (const u32x4*)eapk,
                                                      bf2, bs2, g2, be2,
                                                      nullptr, h1, h2);

    // ---- GCN layer 3 ----
    pack_t_kernel<<<(256 * 512 + B - 1) / B, B, 0, stream>>>(W3, wpack, 512, 256);
    gemm_bt_kernel<<<dim3(NPAD / 128, 2), B, 0, stream>>>(h2, wpack, nullptr, pre_b, NPAD, 256, 512, nullptr);
    gcn_gather_kernel<<<NPAD / 4, B, 0, stream>>>(pre_b, row_ptr, csr_src, dinv, b3, h3, (float*)nullptr);

    // ---- GCN layer 4 ----
    pack_t_kernel<<<(256 * 256 + B - 1) / B, B, 0, stream>>>(W4, wpack, 256, 256);
    gemm_bt_kernel<<<dim3(NPAD / 128, 2), B, 0, stream>>>(h3, wpack, nullptr, pre_b, NPAD, 256, 256, nullptr);
    gcn_gather_kernel<<<NPAD / 4, B, 0, stream>>>(pre_b, row_ptr, csr_src, dinv, b4, h4, outp + NNODES);

    // ---- distance MLP (bias+ReLU fused into GEMM epilogue) ----
    build_zc_kernel<<<(unsigned)(((long)NPAD * 768 + B - 1) / B), B, 0, stream>>>(h4, goal, zc);
    pack_t_kernel<<<(512 * 768 + B - 1) / B, B, 0, stream>>>(Wd1, wpack, 768, 512);
    gemm_bt_kernel<<<dim3(NPAD / 128, 4), B, 0, stream>>>(zc, wpack, nullptr, tb, NPAD, 512, 768, bd1);
    final_dot_kernel<<<512, B, 0, stream>>>(tb, Wd2, bd2, outp);
}

// Round 8
// 757.351 us; speedup vs baseline: 1.0736x; 1.0354x over previous
//
#include <hip/hip_runtime.h>
#include <stdint.h>

#define NNODES 20000
#define NEDGES 160000
#define NPAD   20096   // 157 * 128

typedef float f32x4 __attribute__((ext_vector_type(4)));
typedef float f32x2 __attribute__((ext_vector_type(2)));
typedef short s16x8 __attribute__((ext_vector_type(8)));
typedef unsigned int u32x4 __attribute__((ext_vector_type(4)));
typedef _Float16 h16x2 __attribute__((ext_vector_type(2)));

#define L2E 1.44269504088896340736f
#define LN2 0.6931471805599453f

__device__ __forceinline__ float b2f(unsigned short b) {
    unsigned int u = ((unsigned int)b) << 16;
    return __builtin_bit_cast(float, u);
}
__device__ __forceinline__ unsigned short f2b(float f) {
    unsigned int u = __builtin_bit_cast(unsigned int, f);
    unsigned int r = (u + 0x7FFFu + ((u >> 16) & 1u)) >> 16;
    return (unsigned short)r;
}
// unpack 2 bf16 (packed in a dword) -> float2
__device__ __forceinline__ f32x2 unpack2(unsigned int u) {
    f32x2 r;
    r.x = __builtin_bit_cast(float, u << 16);
    r.y = __builtin_bit_cast(float, u & 0xFFFF0000u);
    return r;
}
// pack two fp32 -> fp16 pair in a dword
__device__ __forceinline__ unsigned int packh2(float a, float b) {
    h16x2 h = { (_Float16)a, (_Float16)b };
    return __builtin_bit_cast(unsigned int, h);
}
// fp16-pair dot with fp32 accumulate: one v_dot2_f32_f16
__device__ __forceinline__ float dot2h(unsigned int a, unsigned int b, float c) {
#if __has_builtin(__builtin_amdgcn_fdot2)
    return __builtin_amdgcn_fdot2(__builtin_bit_cast(h16x2, a),
                                  __builtin_bit_cast(h16x2, b), c, false);
#else
    float d;
    asm("v_dot2_f32_f16 %0, %1, %2, %3" : "=v"(d) : "v"(a), "v"(b), "v"(c));
    return d;
#endif
}
__device__ __forceinline__ float exp2f_fast(float x) {
#if __has_builtin(__builtin_amdgcn_exp2f)
    return __builtin_amdgcn_exp2f(x);
#else
    return __builtin_exp2f(x);
#endif
}
__device__ __forceinline__ float log2f_fast(float x) {
#if __has_builtin(__builtin_amdgcn_logf)
    return __builtin_amdgcn_logf(x);
#else
    return __builtin_log2f(x);
#endif
}

// ---- GEMM: C[M,N] = A[M,K](bf16) @ BT[N,K]^T(bf16); C fp32 or bf16 ----
// BK=64 + XOR bank-conflict swizzle (pre-swizzled global chunk, swizzled read).
__global__ __launch_bounds__(256) void gemm_bt_kernel(
    const unsigned short* __restrict__ A,
    const unsigned short* __restrict__ BT,
    float* __restrict__ Cf,
    unsigned short* __restrict__ Cb,
    int M, int N, int K,
    const float* __restrict__ bias)
{
    __shared__ unsigned short As[128 * 64];
    __shared__ unsigned short Bs[128 * 64];
    const int tid  = threadIdx.x;
    const int wid  = tid >> 6;
    const int lane = tid & 63;
    const int bm = blockIdx.x * 128;
    const int bn = blockIdx.y * 128;
    const int wm = (wid & 1) * 64;
    const int wn = (wid >> 1) * 64;

    f32x4 acc[4][4];
#pragma unroll
    for (int i = 0; i < 4; i++)
#pragma unroll
        for (int j = 0; j < 4; j++) acc[i][j] = {0.f, 0.f, 0.f, 0.f};

    for (int k0 = 0; k0 < K; k0 += 64) {
#pragma unroll
        for (int r = 0; r < 4; r++) {
            int flat = r * 256 + tid;       // 0..1023
            int row  = flat >> 3;           // 128 rows
            int part = flat & 7;            // 8 x 16B chunks per row
            int pg   = part ^ (row & 7);    // pre-swizzled global chunk
            const unsigned short* ga = A  + (size_t)(bm + row) * K + k0 + pg * 8;
            const unsigned short* gb = BT + (size_t)(bn + row) * K + k0 + pg * 8;
            __builtin_amdgcn_global_load_lds(
                (const __attribute__((address_space(1))) unsigned int*)ga,
                (__attribute__((address_space(3))) unsigned int*)&As[flat * 8], 16, 0, 0);
            __builtin_amdgcn_global_load_lds(
                (const __attribute__((address_space(1))) unsigned int*)gb,
                (__attribute__((address_space(3))) unsigned int*)&Bs[flat * 8], 16, 0, 0);
        }
        __syncthreads();

        const int kq8 = lane >> 4;     // 0..3
        const int rl  = lane & 15;
#pragma unroll
        for (int kk = 0; kk < 2; kk++) {
            s16x8 af[4], bfr[4];
#pragma unroll
            for (int mi = 0; mi < 4; mi++) {
                int row = wm + mi * 16 + rl;
                int slot = (kk * 4 + kq8) ^ (row & 7);
                af[mi] = *(const s16x8*)&As[row * 64 + slot * 8];
            }
#pragma unroll
            for (int ni = 0; ni < 4; ni++) {
                int row = wn + ni * 16 + rl;
                int slot = (kk * 4 + kq8) ^ (row & 7);
                bfr[ni] = *(const s16x8*)&Bs[row * 64 + slot * 8];
            }
#pragma unroll
            for (int mi = 0; mi < 4; mi++)
#pragma unroll
                for (int ni = 0; ni < 4; ni++)
                    acc[mi][ni] = __builtin_amdgcn_mfma_f32_16x16x32_bf16(
                        af[mi], bfr[ni], acc[mi][ni], 0, 0, 0);
        }
        __syncthreads();
    }

    const int cl = lane & 15;
    const int rq = (lane >> 4) * 4;
#pragma unroll
    for (int mi = 0; mi < 4; mi++)
#pragma unroll
        for (int ni = 0; ni < 4; ni++)
#pragma unroll
            for (int r = 0; r < 4; r++) {
                int row = bm + wm + mi * 16 + rq + r;
                int col = bn + wn + ni * 16 + cl;
                float v = acc[mi][ni][r];
                if (Cb) {
                    if (bias) v = fmaxf(v + bias[col], 0.f);
                    Cb[(size_t)row * N + col] = f2b(v);
                } else {
                    Cf[(size_t)row * N + col] = v;
                }
            }
}

// ---------------- CSR build ----------------
__global__ void count_kernel(const int* __restrict__ ei, int* __restrict__ counts) {
    int e = blockIdx.x * blockDim.x + threadIdx.x;
    if (e < NEDGES) atomicAdd(&counts[ei[NEDGES + e]], 1);
}

__global__ __launch_bounds__(1024) void scan_kernel(const int* __restrict__ counts,
                                                    int* __restrict__ row_ptr)
{
    __shared__ int sdata[1024];
    const int t = threadIdx.x;
    int vals[20];
    const int base = t * 20;
    int lsum = 0;
#pragma unroll
    for (int j = 0; j < 20; j++) {
        int idx = base + j;
        int v = (idx < NNODES) ? counts[idx] : 0;
        vals[j] = v; lsum += v;
    }
    sdata[t] = lsum;
    __syncthreads();
    for (int off = 1; off < 1024; off <<= 1) {
        int v = (t >= off) ? sdata[t - off] : 0;
        __syncthreads();
        sdata[t] += v;
        __syncthreads();
    }
    int run = sdata[t] - lsum;
#pragma unroll
    for (int j = 0; j < 20; j++) {
        int idx = base + j;
        if (idx < NNODES) row_ptr[idx] = run;
        run += vals[j];
    }
    if (t == 1023) row_ptr[NNODES] = sdata[1023];
}

__global__ void fill_kernel(const int* __restrict__ ei,
                            const int* __restrict__ row_ptr,
                            int* __restrict__ cursor,
                            int* __restrict__ csr_src,
                            int* __restrict__ csr_eid)
{
    int e = blockIdx.x * blockDim.x + threadIdx.x;
    if (e >= NEDGES) return;
    int dst = ei[NEDGES + e];
    int p = row_ptr[dst] + atomicAdd(&cursor[dst], 1);
    csr_src[p] = ei[e];
    csr_eid[p] = e;
}

__global__ void dinv_kernel(const int* __restrict__ row_ptr, float* __restrict__ dinv) {
    int i = blockIdx.x * blockDim.x + threadIdx.x;
    if (i < NNODES) {
        int deg = row_ptr[i + 1] - row_ptr[i] + 1;   // + self loop
        dinv[i] = rsqrtf((float)deg);
    }
}

// ---------------- packing ----------------
__global__ void pad_copy_kernel(const float* __restrict__ src,
                                unsigned short* __restrict__ dst,
                                int valid_rows, int cols, long total)
{
    long idx = (long)blockIdx.x * blockDim.x + threadIdx.x;
    if (idx >= total) return;
    int n = (int)(idx / cols);
    dst[idx] = (n < valid_rows) ? f2b(src[idx]) : (unsigned short)0;
}

// Interleaved P column layout; values pre-scaled by log2(e) (base-2 gather).
__global__ void pack_cgw_kernel(const float* __restrict__ Wf,
                                const float* __restrict__ Ws,
                                unsigned short* __restrict__ out)
{
    int idx = blockIdx.x * blockDim.x + threadIdx.x;
    if (idx >= 2048 * 512) return;
    int j = idx >> 9;          // output column (wpack row) 0..2047
    int k = idx & 511;         // K index
    int half = (j >= 1024);    // 0 = dst block, 1 = src block
    int jj = j & 1023;
    int c  = (jj >> 2) * 2 + (jj & 1);   // channel
    int fs = (jj >> 1) & 1;              // 0 = f, 1 = s
    const float* W = fs ? Ws : Wf;
    float v = W[(size_t)(half ? 512 + k : k) * 512 + c] * L2E;
    out[idx] = f2b(v);
}

__global__ void pack_t_kernel(const float* __restrict__ W,
                              unsigned short* __restrict__ WT,
                              int K, int Nout)
{
    long idx = (long)blockIdx.x * blockDim.x + threadIdx.x;
    if (idx >= (long)K * Nout) return;
    int j = (int)(idx / K);
    int k = (int)(idx % K);
    WT[idx] = f2b(W[(size_t)k * Nout + j]);
}

// W_e table, THREAD-MAJOR: dword idx = tid*32 + k*4 + q (128 B/thread).
// q: 0=f@c0 1=f@c1 2=s@c0 3=s@c1 (c0 = 2*tid); pre-scaled by log2(e).
__global__ void pack_we_kernel(const float* __restrict__ Wf,
                               const float* __restrict__ Ws,
                               unsigned int* __restrict__ out)
{
    int idx = blockIdx.x * blockDim.x + threadIdx.x;
    if (idx >= 8192) return;
    int tid = idx >> 5;
    int r   = idx & 31;
    int k   = r >> 2;
    int q   = r & 3;
    const float* W = (q >> 1) ? Ws : Wf;
    int c = tid * 2 + (q & 1);
    float v0 = W[(size_t)(1024 + 2 * k) * 512 + c] * L2E;
    float v1 = W[(size_t)(1024 + 2 * k + 1) * 512 + c] * L2E;
    out[idx] = packh2(v0, v1);
}

// edge attrs as fp16 pairs in CSR order: eapk[i][j] = (ea[eid][2j], ea[eid][2j+1])
__global__ void pack_ea_kernel(const int* __restrict__ csr_eid,
                               const float* __restrict__ ea,
                               unsigned int* __restrict__ out)
{
    int idx = blockIdx.x * blockDim.x + threadIdx.x;
    if (idx >= NEDGES * 8) return;
    int i = idx >> 3;
    int j = idx & 7;
    int eid = csr_eid[i];
    out[idx] = packh2(ea[(size_t)eid * 16 + 2 * j], ea[(size_t)eid * 16 + 2 * j + 1]);
}

// ---------------- CGConv gather ----------------
// R8: kill the per-edge dependent chain csr[i](VMEM)->readfirstlane->gather.
// A node's CSR entries are contiguous -> ONE coalesced lane-indexed load gets
// all (<=64) edge srcs; per edge, sx comes from v_readlane (2cyc) instead of a
// VMEM round trip. Loop bounds via readfirstlane so the readlane index is SGPR.
// Weights: R7 asm-volatile block, consumed as NAMED scalars (no array).
// Base-2 transcendentals (inputs pre-scaled; ln2 folded into BN gamma).
#define CG_NPB 4

#define CG_LOADE(q_, a0_, a1_, jj) do {                                        \
    int sx_ = __builtin_amdgcn_readlane(sxv, (jj));                            \
    q_  = *(const uint2*)(P + (size_t)sx_ * 2048 + 1024 + c0 * 2);             \
    a0_ = eapk[(size_t)(base + (jj)) * 2];                                     \
    a1_ = eapk[(size_t)(base + (jj)) * 2 + 1];                                 \
} while (0)

#define CG_COMP(q_, a0_, a1_) do {                                             \
    float f0 = baseF.x, f1 = baseF.y, s0 = baseS.x, s1 = baseS.y;              \
    f0 = dot2h(a0_[0], w0[0], f0); f1 = dot2h(a0_[0], w0[1], f1);              \
    s0 = dot2h(a0_[0], w0[2], s0); s1 = dot2h(a0_[0], w0[3], s1);              \
    f0 = dot2h(a0_[1], w1[0], f0); f1 = dot2h(a0_[1], w1[1], f1);              \
    s0 = dot2h(a0_[1], w1[2], s0); s1 = dot2h(a0_[1], w1[3], s1);              \
    f0 = dot2h(a0_[2], w2[0], f0); f1 = dot2h(a0_[2], w2[1], f1);              \
    s0 = dot2h(a0_[2], w2[2], s0); s1 = dot2h(a0_[2], w2[3], s1);              \
    f0 = dot2h(a0_[3], w3[0], f0); f1 = dot2h(a0_[3], w3[1], f1);              \
    s0 = dot2h(a0_[3], w3[2], s0); s1 = dot2h(a0_[3], w3[3], s1);              \
    f0 = dot2h(a1_[0], w4[0], f0); f1 = dot2h(a1_[0], w4[1], f1);              \
    s0 = dot2h(a1_[0], w4[2], s0); s1 = dot2h(a1_[0], w4[3], s1);              \
    f0 = dot2h(a1_[1], w5[0], f0); f1 = dot2h(a1_[1], w5[1], f1);              \
    s0 = dot2h(a1_[1], w5[2], s0); s1 = dot2h(a1_[1], w5[3], s1);              \
    f0 = dot2h(a1_[2], w6[0], f0); f1 = dot2h(a1_[2], w6[1], f1);              \
    s0 = dot2h(a1_[2], w6[2], s0); s1 = dot2h(a1_[2], w6[3], s1);              \
    f0 = dot2h(a1_[3], w7[0], f0); f1 = dot2h(a1_[3], w7[1], f1);              \
    s0 = dot2h(a1_[3], w7[2], s0); s1 = dot2h(a1_[3], w7[3], s1);              \
    f32x2 pf = unpack2(q_.x);                                                  \
    f32x2 ps = unpack2(q_.y);                                                  \
    f0 += pf.x; f1 += pf.y; s0 += ps.x; s1 += ps.y;                            \
    float sp0 = log2f_fast(1.f + exp2f_fast(s0));                              \
    float sp1 = log2f_fast(1.f + exp2f_fast(s1));                              \
    float sg0 = __builtin_amdgcn_rcpf(1.f + exp2f_fast(-f0));                  \
    float sg1 = __builtin_amdgcn_rcpf(1.f + exp2f_fast(-f1));                  \
    acc.x = fmaf(sp0, sg0, acc.x);                                             \
    acc.y = fmaf(sp1, sg1, acc.y);                                             \
} while (0)

__global__ __launch_bounds__(256, 1) void cg_gather_kernel(
    const unsigned short* __restrict__ P,
    const int* __restrict__ row_ptr,
    const int* __restrict__ csr_src,
    const unsigned int* __restrict__ wE,   // [256][8][4] dwords, thread-major
    const u32x4* __restrict__ eapk,        // [NEDGES][2] fp16-pair attrs, CSR order
    const float* __restrict__ bfv,
    const float* __restrict__ bsv,
    const float* __restrict__ g,
    const float* __restrict__ be,
    const float* __restrict__ xresf,          // fp32 [NNODES,512] or null
    const unsigned short* __restrict__ xresb, // bf16 [NPAD,512] or null
    unsigned short* __restrict__ hout)
{
    const int tid  = threadIdx.x;
    const int lane = tid & 63;
    const int c0  = tid * 2;
    const int nbase = blockIdx.x * CG_NPB;

    // ---- register-resident weight table (asm volatile: cannot rematerialize)
    const unsigned int* wp = wE + (size_t)tid * 32;   // 128 B per thread
    u32x4 w0, w1, w2, w3, w4, w5, w6, w7;
    asm volatile(
        "global_load_dwordx4 %0, %8, off\n\t"
        "global_load_dwordx4 %1, %8, off offset:16\n\t"
        "global_load_dwordx4 %2, %8, off offset:32\n\t"
        "global_load_dwordx4 %3, %8, off offset:48\n\t"
        "global_load_dwordx4 %4, %8, off offset:64\n\t"
        "global_load_dwordx4 %5, %8, off offset:80\n\t"
        "global_load_dwordx4 %6, %8, off offset:96\n\t"
        "global_load_dwordx4 %7, %8, off offset:112\n\t"
        "s_waitcnt vmcnt(0)"
        : "=&v"(w0), "=&v"(w1), "=&v"(w2), "=&v"(w3),
          "=&v"(w4), "=&v"(w5), "=&v"(w6), "=&v"(w7)
        : "v"(wp));
    __builtin_amdgcn_sched_barrier(0);

    const f32x2 bfx = *(const f32x2*)&bfv[c0] * L2E;
    const f32x2 bsx = *(const f32x2*)&bsv[c0] * L2E;
    const f32x2 gv  = *(const f32x2*)&g[c0];
    const f32x2 bev = *(const f32x2*)&be[c0];
    const float rsl = rsqrtf(1.f + 1e-5f) * LN2;   // BN rs * ln2 (base-2 fold)

    for (int n = nbase; n < nbase + CG_NPB; n++) {
        if (n >= NNODES) {
            *(unsigned int*)&hout[(size_t)n * 512 + c0] = 0;
            continue;
        }
        const unsigned short* Pd = P + (size_t)n * 2048;
        const uint2 qb = *(const uint2*)(Pd + c0 * 2);
        const f32x2 baseF = unpack2(qb.x) + bfx;
        const f32x2 baseS = unpack2(qb.y) + bsx;

        f32x2 acc = {0.f, 0.f};
        const int i0 = __builtin_amdgcn_readfirstlane(row_ptr[n]);
        const int i1 = __builtin_amdgcn_readfirstlane(row_ptr[n + 1]);

        for (int base = i0; base < i1; base += 64) {
            const int cnt = min(64, i1 - base);
            int idxc = base + lane;
            if (idxc >= NEDGES) idxc = NEDGES - 1;
            const int sxv = csr_src[idxc];   // one coalesced load: all edge srcs

            uint2 qA = {}, qB = {};
            u32x4 aA0 = {}, aA1 = {}, aB0 = {}, aB1 = {};
            CG_LOADE(qA, aA0, aA1, 0);
            if (cnt > 1) CG_LOADE(qB, aB0, aB1, 1);
            int j = 0;
            while (true) {
                CG_COMP(qA, aA0, aA1);
                if (j + 2 < cnt) CG_LOADE(qA, aA0, aA1, j + 2);
                if (++j >= cnt) break;
                CG_COMP(qB, aB0, aB1);
                if (j + 2 < cnt) CG_LOADE(qB, aB0, aB1, j + 2);
                if (++j >= cnt) break;
            }
        }

        // fused BN(eval) + residual + ReLU  (acc carries log2-form softplus)
        f32x2 res;
        if (xresf) {
            res = *(const f32x2*)&xresf[(size_t)n * 512 + c0];
        } else {
            res = unpack2(*(const unsigned int*)&xresb[(size_t)n * 512 + c0]);
        }
        float v0 = fmaxf(acc.x * (gv.x * rsl) + bev.x + res.x, 0.f);
        float v1 = fmaxf(acc.y * (gv.y * rsl) + bev.y + res.y, 0.f);
        unsigned int packed = (unsigned int)f2b(v0) | ((unsigned int)f2b(v1) << 16);
        *(unsigned int*)&hout[(size_t)n * 512 + c0] = packed;
    }
}

// ---------------- GCN gather (1 wave/node; csr+dinv pre-gathered lanewise) ----
__global__ __launch_bounds__(256) void gcn_gather_kernel(
    const unsigned short* __restrict__ pre,   // bf16 [NPAD,256]
    const int* __restrict__ row_ptr,
    const int* __restrict__ csr_src,
    const float* __restrict__ dinv,
    const float* __restrict__ b,
    unsigned short* __restrict__ hout,  // bf16 [NPAD,256]
    float* __restrict__ doutf)          // fp32 [NNODES,256] or null
{
    const int tid  = threadIdx.x;
    const int lane = tid & 63;
    const int n = blockIdx.x * 4 + (tid >> 6);   // one wave per node
    const int c = lane * 4;                      // 4 channels per thread
    if (n >= NNODES) {
        if (n < NPAD) { uint2 z = {0u, 0u}; *(uint2*)&hout[(size_t)n * 256 + c] = z; }
        return;
    }
    const float din = dinv[n];
    f32x4 acc = {0.f, 0.f, 0.f, 0.f};
    const int i0 = __builtin_amdgcn_readfirstlane(row_ptr[n]);
    const int i1 = __builtin_amdgcn_readfirstlane(row_ptr[n + 1]);

#define GCN_LD(pv_, jj) do {                                                   \
    int sx_ = __builtin_amdgcn_readlane(sxv, (jj));                            \
    pv_ = *(const uint2*)&pre[(size_t)sx_ * 256 + c];                          \
} while (0)

#define GCN_CP(pv_, jj) do {                                                   \
    float dv_ = __builtin_bit_cast(float, __builtin_amdgcn_readlane(dvb, (jj)));\
    f32x2 p0 = unpack2(pv_.x);                                                 \
    f32x2 p1 = unpack2(pv_.y);                                                 \
    acc.x = fmaf(dv_, p0.x, acc.x);                                            \
    acc.y = fmaf(dv_, p0.y, acc.y);                                            \
    acc.z = fmaf(dv_, p1.x, acc.z);                                            \
    acc.w = fmaf(dv_, p1.y, acc.w);                                            \
} while (0)

    for (int base = i0; base < i1; base += 64) {
        const int cnt = min(64, i1 - base);
        int idxc = base + lane;
        if (idxc >= NEDGES) idxc = NEDGES - 1;
        const int sxv = csr_src[idxc];            // all edge srcs, one load
        const int dvb = __builtin_bit_cast(int, dinv[sxv]);  // all dinv, one gather

        uint2 pvA = {}, pvB = {}, pvC = {};
        GCN_LD(pvA, 0);
        if (cnt > 1) GCN_LD(pvB, 1);
        if (cnt > 2) GCN_LD(pvC, 2);
        int j = 0;
        while (true) {
            GCN_CP(pvA, j);
            if (j + 3 < cnt) GCN_LD(pvA, j + 3);
            if (++j >= cnt) break;
            GCN_CP(pvB, j);
            if (j + 3 < cnt) GCN_LD(pvB, j + 3);
            if (++j >= cnt) break;
            GCN_CP(pvC, j);
            if (j + 3 < cnt) GCN_LD(pvC, j + 3);
            if (++j >= cnt) break;
        }
    }
    uint2 sv = *(const uint2*)&pre[(size_t)n * 256 + c];
    f32x2 s0 = unpack2(sv.x);
    f32x2 s1 = unpack2(sv.y);
    const f32x4 bv = *(const f32x4*)&b[c];
    const float d2 = din * din;
    float v0 = fmaxf(fmaf(acc.x, din, d2 * s0.x) + bv.x, 0.f);
    float v1 = fmaxf(fmaf(acc.y, din, d2 * s0.y) + bv.y, 0.f);
    float v2 = fmaxf(fmaf(acc.z, din, d2 * s1.x) + bv.z, 0.f);
    float v3 = fmaxf(fmaf(acc.w, din, d2 * s1.y) + bv.w, 0.f);
    uint2 o;
    o.x = (unsigned int)f2b(v0) | ((unsigned int)f2b(v1) << 16);
    o.y = (unsigned int)f2b(v2) | ((unsigned int)f2b(v3) << 16);
    *(uint2*)&hout[(size_t)n * 256 + c] = o;
    if (doutf) {
        f32x4 vv = {v0, v1, v2, v3};
        *(f32x4*)&doutf[(size_t)n * 256 + c] = vv;
    }
}

// ---------------- MLP ----------------
__global__ void build_zc_kernel(const unsigned short* __restrict__ h4,
                                const float* __restrict__ goal,
                                unsigned short* __restrict__ zc)
{
    long idx = (long)blockIdx.x * blockDim.x + threadIdx.x;
    if (idx >= (long)NPAD * 768) return;
    int n = (int)(idx / 768);
    int c = (int)(idx % 768);
    unsigned short v = 0;
    if (n < NNODES)
        v = (c < 256) ? h4[(size_t)n * 256 + c]
                      : f2b(goal[(size_t)n * 512 + (c - 256)]);
    zc[idx] = v;
}

__global__ __launch_bounds__(256) void final_dot_kernel(
    const unsigned short* __restrict__ t,
    const float* __restrict__ Wd2,
    const float* __restrict__ bd2,
    float* __restrict__ pred)
{
    const int lane = threadIdx.x & 63;
    const int wid  = threadIdx.x >> 6;
    float w[8];
#pragma unroll
    for (int i = 0; i < 8; i++) w[i] = Wd2[lane * 8 + i];
    const float bd = bd2[0];
    for (int n = blockIdx.x * 4 + wid; n < NNODES; n += gridDim.x * 4) {
        const unsigned short* tp = t + (size_t)n * 512 + lane * 8;
        float s = 0.f;
#pragma unroll
        for (int i = 0; i < 8; i++) s = fmaf(b2f(tp[i]), w[i], s);
#pragma unroll
        for (int off = 32; off; off >>= 1) s += __shfl_xor(s, off, 64);
        if (lane == 0) pred[n] = s + bd;
    }
}

// ---------------- launcher ----------------
extern "C" void kernel_launch(void* const* d_in, const int* in_sizes, int n_in,
                              void* d_out, int out_size, void* d_ws, size_t ws_size,
                              hipStream_t stream)
{
    (void)in_sizes; (void)n_in; (void)out_size; (void)ws_size;
    const float* x    = (const float*)d_in[0];
    const int*   ei   = (const int*)d_in[1];
    const float* ea   = (const float*)d_in[2];
    const float* goal = (const float*)d_in[3];
    const float* Wf1  = (const float*)d_in[4];
    const float* bf1  = (const float*)d_in[5];
    const float* Ws1  = (const float*)d_in[6];
    const float* bs1  = (const float*)d_in[7];
    const float* g1   = (const float*)d_in[8];
    const float* be1  = (const float*)d_in[9];
    const float* Wf2  = (const float*)d_in[10];
    const float* bf2  = (const float*)d_in[11];
    const float* Ws2  = (const float*)d_in[12];
    const float* bs2  = (const float*)d_in[13];
    const float* g2   = (const float*)d_in[14];
    const float* be2  = (const float*)d_in[15];
    const float* W3   = (const float*)d_in[16];
    const float* b3   = (const float*)d_in[17];
    const float* W4   = (const float*)d_in[18];
    const float* b4   = (const float*)d_in[19];
    const float* Wd1  = (const float*)d_in[20];
    const float* bd1  = (const float*)d_in[21];
    const float* Wd2  = (const float*)d_in[22];
    const float* bd2  = (const float*)d_in[23];
    float* outp = (float*)d_out;   // fp32: [0..N) pred, [N..N+N*256) h

    char* ws = (char*)d_ws;
    size_t off = 0;
    auto alloc = [&](size_t bytes) -> char* {
        char* p = ws + off;
        off += (bytes + 255) & ~(size_t)255;
        return p;
    };
    unsigned short* P     = (unsigned short*)alloc((size_t)NPAD * 2048 * 2); // later zc + tb
    unsigned short* bufA  = (unsigned short*)alloc((size_t)NPAD * 512 * 2);  // xpad / h2 / h4
    unsigned short* bufB  = (unsigned short*)alloc((size_t)NPAD * 512 * 2);  // h1 / pre_b
    unsigned short* bufC  = (unsigned short*)alloc((size_t)NPAD * 512 * 2);  // h3
    unsigned short* wpack = (unsigned short*)alloc((size_t)2048 * 512 * 2);
    int*            counts  = (int*)alloc((size_t)NNODES * 4);
    int*            row_ptr = (int*)alloc((size_t)(NNODES + 1) * 4);
    int*            csr_src = (int*)alloc((size_t)NEDGES * 4);
    int*            csr_eid = (int*)alloc((size_t)NEDGES * 4);
    float*          dinv    = (float*)alloc((size_t)NNODES * 4);
    unsigned int*   wEbuf   = (unsigned int*)alloc((size_t)8192 * 4);
    unsigned int*   eapk    = (unsigned int*)alloc((size_t)NEDGES * 8 * 4);

    unsigned short* xpad  = bufA;
    unsigned short* h1    = bufB;
    unsigned short* h2    = bufA;
    unsigned short* pre_b = bufB;
    unsigned short* h3    = bufC;
    unsigned short* h4    = bufA;
    unsigned short* zc    = P;
    unsigned short* tb    = P + (size_t)NPAD * 1024;

    const int B = 256;

    // ---- CSR build (by destination) + dinv ----
    hipMemsetAsync(counts, 0, (size_t)NNODES * 4, stream);
    count_kernel<<<(NEDGES + B - 1) / B, B, 0, stream>>>(ei, counts);
    scan_kernel<<<1, 1024, 0, stream>>>(counts, row_ptr);
    hipMemsetAsync(counts, 0, (size_t)NNODES * 4, stream);
    fill_kernel<<<(NEDGES + B - 1) / B, B, 0, stream>>>(ei, row_ptr, counts, csr_src, csr_eid);
    dinv_kernel<<<(NNODES + B - 1) / B, B, 0, stream>>>(row_ptr, dinv);
    pack_ea_kernel<<<(NEDGES * 8 + B - 1) / B, B, 0, stream>>>(csr_eid, ea, eapk);

    {
        long tot = (long)NPAD * 512;
        pad_copy_kernel<<<(unsigned)((tot + B - 1) / B), B, 0, stream>>>(x, xpad, NNODES, 512, tot);
    }

    dim3 gBig(NPAD / 128, 2048 / 128);

    // ---- CGConv layer 1 ----
    pack_cgw_kernel<<<(2048 * 512 + B - 1) / B, B, 0, stream>>>(Wf1, Ws1, wpack);
    pack_we_kernel<<<(8192 + B - 1) / B, B, 0, stream>>>(Wf1, Ws1, wEbuf);
    gemm_bt_kernel<<<gBig, B, 0, stream>>>(xpad, wpack, nullptr, P, NPAD, 2048, 512, nullptr);
    cg_gather_kernel<<<NPAD / CG_NPB, B, 0, stream>>>(P, row_ptr, csr_src,
                                                      wEbuf, (const u32x4*)eapk,
                                                      bf1, bs1, g1, be1,
                                                      x, nullptr, h1);

    // ---- CGConv layer 2 ----
    pack_cgw_kernel<<<(2048 * 512 + B - 1) / B, B, 0, stream>>>(Wf2, Ws2, wpack);
    gemm_bt_kernel<<<gBig, B, 0, stream>>>(h1, wpack, nullptr, P, NPAD, 2048, 512, nullptr);
    pack_we_kernel<<<(8192 + B - 1) / B, B, 0, stream>>>(Wf2, Ws2, wEbuf);
    cg_gather_kernel<<<NPAD / CG_NPB, B, 0, stream>>>(P, row_ptr, csr_src,
                                                      wEbuf, (const u32x4*)eapk,
                                                      bf2, bs2, g2, be2,
                                                      nullptr, h1, h2);

    // ---- GCN layer 3 ----
    pack_t_kernel<<<(256 * 512 + B - 1) / B, B, 0, stream>>>(W3, wpack, 512, 256);
    gemm_bt_kernel<<<dim3(NPAD / 128, 2), B, 0, stream>>>(h2, wpack, nullptr, pre_b, NPAD, 256, 512, nullptr);
    gcn_gather_kernel<<<NPAD / 4, B, 0, stream>>>(pre_b, row_ptr, csr_src, dinv, b3, h3, (float*)nullptr);

    // ---- GCN layer 4 ----
    pack_t_kernel<<<(256 * 256 + B - 1) / B, B, 0, stream>>>(W4, wpack, 256, 256);
    gemm_bt_kernel<<<dim3(NPAD / 128, 2), B, 0, stream>>>(h3, wpack, nullptr, pre_b, NPAD, 256, 256, nullptr);
    gcn_gather_kernel<<<NPAD / 4, B, 0, stream>>>(pre_b, row_ptr, csr_src, dinv, b4, h4, outp + NNODES);

    // ---- distance MLP (bias+ReLU fused into GEMM epilogue) ----
    build_zc_kernel<<<(unsigned)(((long)NPAD * 768 + B - 1) / B), B, 0, stream>>>(h4, goal, zc);
    pack_t_kernel<<<(512 * 768 + B - 1) / B, B, 0, stream>>>(Wd1, wpack, 768, 512);
    gemm_bt_kernel<<<dim3(NPAD / 128, 4), B, 0, stream>>>(zc, wpack, nullptr, tb, NPAD, 512, 768, bd1);
    final_dot_kernel<<<512, B, 0, stream>>>(tb, Wd2, bd2, outp);
}

// Round 9
// 751.785 us; speedup vs baseline: 1.0815x; 1.0074x over previous
//
#include <hip/hip_runtime.h>
#include <stdint.h>

#define NNODES 20000
#define NEDGES 160000
#define NPAD   20096   // 157 * 128

typedef float f32x4 __attribute__((ext_vector_type(4)));
typedef float f32x2 __attribute__((ext_vector_type(2)));
typedef short s16x8 __attribute__((ext_vector_type(8)));
typedef unsigned int u32x4 __attribute__((ext_vector_type(4)));
typedef _Float16 h16x2 __attribute__((ext_vector_type(2)));

#define L2E 1.44269504088896340736f
#define LN2 0.6931471805599453f

__device__ __forceinline__ float b2f(unsigned short b) {
    unsigned int u = ((unsigned int)b) << 16;
    return __builtin_bit_cast(float, u);
}
__device__ __forceinline__ unsigned short f2b(float f) {
    unsigned int u = __builtin_bit_cast(unsigned int, f);
    unsigned int r = (u + 0x7FFFu + ((u >> 16) & 1u)) >> 16;
    return (unsigned short)r;
}
// unpack 2 bf16 (packed in a dword) -> float2
__device__ __forceinline__ f32x2 unpack2(unsigned int u) {
    f32x2 r;
    r.x = __builtin_bit_cast(float, u << 16);
    r.y = __builtin_bit_cast(float, u & 0xFFFF0000u);
    return r;
}
// pack two fp32 -> fp16 pair in a dword
__device__ __forceinline__ unsigned int packh2(float a, float b) {
    h16x2 h = { (_Float16)a, (_Float16)b };
    return __builtin_bit_cast(unsigned int, h);
}
// fp16-pair dot with fp32 accumulate: one v_dot2_f32_f16
__device__ __forceinline__ float dot2h(unsigned int a, unsigned int b, float c) {
#if __has_builtin(__builtin_amdgcn_fdot2)
    return __builtin_amdgcn_fdot2(__builtin_bit_cast(h16x2, a),
                                  __builtin_bit_cast(h16x2, b), c, false);
#else
    float d;
    asm("v_dot2_f32_f16 %0, %1, %2, %3" : "=v"(d) : "v"(a), "v"(b), "v"(c));
    return d;
#endif
}
__device__ __forceinline__ float exp2f_fast(float x) {
#if __has_builtin(__builtin_amdgcn_exp2f)
    return __builtin_amdgcn_exp2f(x);
#else
    return __builtin_exp2f(x);
#endif
}
__device__ __forceinline__ float log2f_fast(float x) {
#if __has_builtin(__builtin_amdgcn_logf)
    return __builtin_amdgcn_logf(x);
#else
    return __builtin_log2f(x);
#endif
}

// ---- GEMM: C[M,N] = A[M,K](bf16) @ BT[N,K]^T(bf16); C fp32 or bf16 ----
// BK=64 + XOR bank-conflict swizzle (pre-swizzled global chunk, swizzled read).
// XCD-aware bijective block swizzle (m204): each XCD gets a contiguous chunk of
// flat block ids; decomposition is bn-fastest so one XCD chunk reuses A-tiles
// from its own L2 (B panel always L2-fits).
__global__ __launch_bounds__(256) void gemm_bt_kernel(
    const unsigned short* __restrict__ A,
    const unsigned short* __restrict__ BT,
    float* __restrict__ Cf,
    unsigned short* __restrict__ Cb,
    int M, int N, int K,
    const float* __restrict__ bias)
{
    __shared__ unsigned short As[128 * 64];
    __shared__ unsigned short Bs[128 * 64];
    const int tid  = threadIdx.x;
    const int wid  = tid >> 6;
    const int lane = tid & 63;

    // ---- XCD-aware bijective swizzle of the flat block id
    const int nwg  = gridDim.x * gridDim.y;
    const int orig = blockIdx.y * gridDim.x + blockIdx.x;  // dispatch order (x fastest)
    const int q = nwg >> 3, r = nwg & 7;
    const int xcd = orig & 7;
    const int idx = orig >> 3;
    const int swz = (xcd < r ? xcd * (q + 1) : r * (q + 1) + (xcd - r) * q) + idx;
    const int bm = (swz / gridDim.y) * 128;
    const int bn = (swz % gridDim.y) * 128;

    const int wm = (wid & 1) * 64;
    const int wn = (wid >> 1) * 64;

    f32x4 acc[4][4];
#pragma unroll
    for (int i = 0; i < 4; i++)
#pragma unroll
        for (int j = 0; j < 4; j++) acc[i][j] = {0.f, 0.f, 0.f, 0.f};

    for (int k0 = 0; k0 < K; k0 += 64) {
#pragma unroll
        for (int rr = 0; rr < 4; rr++) {
            int flat = rr * 256 + tid;      // 0..1023
            int row  = flat >> 3;           // 128 rows
            int part = flat & 7;            // 8 x 16B chunks per row
            int pg   = part ^ (row & 7);    // pre-swizzled global chunk
            const unsigned short* ga = A  + (size_t)(bm + row) * K + k0 + pg * 8;
            const unsigned short* gb = BT + (size_t)(bn + row) * K + k0 + pg * 8;
            __builtin_amdgcn_global_load_lds(
                (const __attribute__((address_space(1))) unsigned int*)ga,
                (__attribute__((address_space(3))) unsigned int*)&As[flat * 8], 16, 0, 0);
            __builtin_amdgcn_global_load_lds(
                (const __attribute__((address_space(1))) unsigned int*)gb,
                (__attribute__((address_space(3))) unsigned int*)&Bs[flat * 8], 16, 0, 0);
        }
        __syncthreads();

        const int kq8 = lane >> 4;     // 0..3
        const int rl  = lane & 15;
#pragma unroll
        for (int kk = 0; kk < 2; kk++) {
            s16x8 af[4], bfr[4];
#pragma unroll
            for (int mi = 0; mi < 4; mi++) {
                int row = wm + mi * 16 + rl;
                int slot = (kk * 4 + kq8) ^ (row & 7);
                af[mi] = *(const s16x8*)&As[row * 64 + slot * 8];
            }
#pragma unroll
            for (int ni = 0; ni < 4; ni++) {
                int row = wn + ni * 16 + rl;
                int slot = (kk * 4 + kq8) ^ (row & 7);
                bfr[ni] = *(const s16x8*)&Bs[row * 64 + slot * 8];
            }
#pragma unroll
            for (int mi = 0; mi < 4; mi++)
#pragma unroll
                for (int ni = 0; ni < 4; ni++)
                    acc[mi][ni] = __builtin_amdgcn_mfma_f32_16x16x32_bf16(
                        af[mi], bfr[ni], acc[mi][ni], 0, 0, 0);
        }
        __syncthreads();
    }

    const int cl = lane & 15;
    const int rq = (lane >> 4) * 4;
#pragma unroll
    for (int mi = 0; mi < 4; mi++)
#pragma unroll
        for (int ni = 0; ni < 4; ni++)
#pragma unroll
            for (int rr = 0; rr < 4; rr++) {
                int row = bm + wm + mi * 16 + rq + rr;
                int col = bn + wn + ni * 16 + cl;
                float v = acc[mi][ni][rr];
                if (Cb) {
                    if (bias) v = fmaxf(v + bias[col], 0.f);
                    Cb[(size_t)row * N + col] = f2b(v);
                } else {
                    Cf[(size_t)row * N + col] = v;
                }
            }
}

// ---------------- CSR build ----------------
__global__ void count_kernel(const int* __restrict__ ei, int* __restrict__ counts) {
    int e = blockIdx.x * blockDim.x + threadIdx.x;
    if (e < NEDGES) atomicAdd(&counts[ei[NEDGES + e]], 1);
}

__global__ __launch_bounds__(1024) void scan_kernel(const int* __restrict__ counts,
                                                    int* __restrict__ row_ptr)
{
    __shared__ int sdata[1024];
    const int t = threadIdx.x;
    int vals[20];
    const int base = t * 20;
    int lsum = 0;
#pragma unroll
    for (int j = 0; j < 20; j++) {
        int idx = base + j;
        int v = (idx < NNODES) ? counts[idx] : 0;
        vals[j] = v; lsum += v;
    }
    sdata[t] = lsum;
    __syncthreads();
    for (int off = 1; off < 1024; off <<= 1) {
        int v = (t >= off) ? sdata[t - off] : 0;
        __syncthreads();
        sdata[t] += v;
        __syncthreads();
    }
    int run = sdata[t] - lsum;
#pragma unroll
    for (int j = 0; j < 20; j++) {
        int idx = base + j;
        if (idx < NNODES) row_ptr[idx] = run;
        run += vals[j];
    }
    if (t == 1023) row_ptr[NNODES] = sdata[1023];
}

__global__ void fill_kernel(const int* __restrict__ ei,
                            const int* __restrict__ row_ptr,
                            int* __restrict__ cursor,
                            int* __restrict__ csr_src,
                            int* __restrict__ csr_eid)
{
    int e = blockIdx.x * blockDim.x + threadIdx.x;
    if (e >= NEDGES) return;
    int dst = ei[NEDGES + e];
    int p = row_ptr[dst] + atomicAdd(&cursor[dst], 1);
    csr_src[p] = ei[e];
    csr_eid[p] = e;
}

__global__ void dinv_kernel(const int* __restrict__ row_ptr, float* __restrict__ dinv) {
    int i = blockIdx.x * blockDim.x + threadIdx.x;
    if (i < NNODES) {
        int deg = row_ptr[i + 1] - row_ptr[i] + 1;   // + self loop
        dinv[i] = rsqrtf((float)deg);
    }
}

// ---------------- packing ----------------
__global__ void pad_copy_kernel(const float* __restrict__ src,
                                unsigned short* __restrict__ dst,
                                int valid_rows, int cols, long total)
{
    long idx = (long)blockIdx.x * blockDim.x + threadIdx.x;
    if (idx >= total) return;
    int n = (int)(idx / cols);
    dst[idx] = (n < valid_rows) ? f2b(src[idx]) : (unsigned short)0;
}

// LDS-tiled TRANSPOSING pack for CGConv GEMM weights (old pack_cgw did fully
// strided 4B reads -- each lane its own cacheline). Coalesced read -> padded
// LDS tile -> coalesced bf16 write. Values pre-scaled by log2(e).
// out[j*512+k] = Wsel(fs)[(half?512+k:k)*512 + c] * L2E,
//   j = half*1024 + (c>>1)*4 + fs*2 + (c&1).
// grid (8,8,4): x=c-tile, y=k-tile, z={fs + 2*half}; block 256 = 64(tx) x 4(ty).
__global__ __launch_bounds__(256) void pack_cgw_kernel(
    const float* __restrict__ Wf,
    const float* __restrict__ Ws,
    unsigned short* __restrict__ out)
{
    __shared__ float tile[64][65];
    const int tx  = threadIdx.x & 63;
    const int ty4 = threadIdx.x >> 6;
    const int c0 = blockIdx.x * 64;
    const int k0 = blockIdx.y * 64;
    const int fs   = blockIdx.z & 1;
    const int half = blockIdx.z >> 1;
    const float* W = fs ? Ws : Wf;
    const float* Wb = W + (size_t)(half ? 512 : 0) * 512;
    for (int rr = ty4; rr < 64; rr += 4)          // rows k, cols c: coalesced
        tile[rr][tx] = Wb[(size_t)(k0 + rr) * 512 + (c0 + tx)];
    __syncthreads();
    for (int rr = ty4; rr < 64; rr += 4) {        // rows j(c), cols k: coalesced
        int c = c0 + rr;
        int j = half * 1024 + (c >> 1) * 4 + fs * 2 + (c & 1);
        out[(size_t)j * 512 + (k0 + tx)] = f2b(tile[tx][rr] * L2E);
    }
}

// LDS-tiled transpose pack: WT[j*K+k] = W[k*Nout+j].
// grid (Nout/64, K/64); block 256 = 64(tx) x 4(ty). K,Nout multiples of 64.
__global__ __launch_bounds__(256) void pack_t_kernel(
    const float* __restrict__ W,
    unsigned short* __restrict__ WT,
    int K, int Nout)
{
    __shared__ float tile[64][65];
    const int tx  = threadIdx.x & 63;
    const int ty4 = threadIdx.x >> 6;
    const int j0 = blockIdx.x * 64;
    const int k0 = blockIdx.y * 64;
    for (int rr = ty4; rr < 64; rr += 4)          // rows k, cols j: coalesced
        tile[rr][tx] = W[(size_t)(k0 + rr) * Nout + (j0 + tx)];
    __syncthreads();
    for (int rr = ty4; rr < 64; rr += 4)          // rows j, cols k: coalesced
        WT[(size_t)(j0 + rr) * K + (k0 + tx)] = f2b(tile[tx][rr]);
}

// W_e table, THREAD-MAJOR: dword idx = tid*32 + k*4 + q (128 B/thread).
// q: 0=f@c0 1=f@c1 2=s@c0 3=s@c1 (c0 = 2*tid); pre-scaled by log2(e).
__global__ void pack_we_kernel(const float* __restrict__ Wf,
                               const float* __restrict__ Ws,
                               unsigned int* __restrict__ out)
{
    int idx = blockIdx.x * blockDim.x + threadIdx.x;
    if (idx >= 8192) return;
    int tid = idx >> 5;
    int r   = idx & 31;
    int k   = r >> 2;
    int q   = r & 3;
    const float* W = (q >> 1) ? Ws : Wf;
    int c = tid * 2 + (q & 1);
    float v0 = W[(size_t)(1024 + 2 * k) * 512 + c] * L2E;
    float v1 = W[(size_t)(1024 + 2 * k + 1) * 512 + c] * L2E;
    out[idx] = packh2(v0, v1);
}

// edge attrs as fp16 pairs in CSR order: eapk[i][j] = (ea[eid][2j], ea[eid][2j+1])
__global__ void pack_ea_kernel(const int* __restrict__ csr_eid,
                               const float* __restrict__ ea,
                               unsigned int* __restrict__ out)
{
    int idx = blockIdx.x * blockDim.x + threadIdx.x;
    if (idx >= NEDGES * 8) return;
    int i = idx >> 3;
    int j = idx & 7;
    int eid = csr_eid[i];
    out[idx] = packh2(ea[(size_t)eid * 16 + 2 * j], ea[(size_t)eid * 16 + 2 * j + 1]);
}

// ---------------- CGConv gather (R8 structure, frozen) ----------------
#define CG_NPB 4

#define CG_LOADE(q_, a0_, a1_, jj) do {                                        \
    int sx_ = __builtin_amdgcn_readlane(sxv, (jj));                            \
    q_  = *(const uint2*)(P + (size_t)sx_ * 2048 + 1024 + c0 * 2);             \
    a0_ = eapk[(size_t)(base + (jj)) * 2];                                     \
    a1_ = eapk[(size_t)(base + (jj)) * 2 + 1];                                 \
} while (0)

#define CG_COMP(q_, a0_, a1_) do {                                             \
    float f0 = baseF.x, f1 = baseF.y, s0 = baseS.x, s1 = baseS.y;              \
    f0 = dot2h(a0_[0], w0[0], f0); f1 = dot2h(a0_[0], w0[1], f1);              \
    s0 = dot2h(a0_[0], w0[2], s0); s1 = dot2h(a0_[0], w0[3], s1);              \
    f0 = dot2h(a0_[1], w1[0], f0); f1 = dot2h(a0_[1], w1[1], f1);              \
    s0 = dot2h(a0_[1], w1[2], s0); s1 = dot2h(a0_[1], w1[3], s1);              \
    f0 = dot2h(a0_[2], w2[0], f0); f1 = dot2h(a0_[2], w2[1], f1);              \
    s0 = dot2h(a0_[2], w2[2], s0); s1 = dot2h(a0_[2], w2[3], s1);              \
    f0 = dot2h(a0_[3], w3[0], f0); f1 = dot2h(a0_[3], w3[1], f1);              \
    s0 = dot2h(a0_[3], w3[2], s0); s1 = dot2h(a0_[3], w3[3], s1);              \
    f0 = dot2h(a1_[0], w4[0], f0); f1 = dot2h(a1_[0], w4[1], f1);              \
    s0 = dot2h(a1_[0], w4[2], s0); s1 = dot2h(a1_[0], w4[3], s1);              \
    f0 = dot2h(a1_[1], w5[0], f0); f1 = dot2h(a1_[1], w5[1], f1);              \
    s0 = dot2h(a1_[1], w5[2], s0); s1 = dot2h(a1_[1], w5[3], s1);              \
    f0 = dot2h(a1_[2], w6[0], f0); f1 = dot2h(a1_[2], w6[1], f1);              \
    s0 = dot2h(a1_[2], w6[2], s0); s1 = dot2h(a1_[2], w6[3], s1);              \
    f0 = dot2h(a1_[3], w7[0], f0); f1 = dot2h(a1_[3], w7[1], f1);              \
    s0 = dot2h(a1_[3], w7[2], s0); s1 = dot2h(a1_[3], w7[3], s1);              \
    f32x2 pf = unpack2(q_.x);                                                  \
    f32x2 ps = unpack2(q_.y);                                                  \
    f0 += pf.x; f1 += pf.y; s0 += ps.x; s1 += ps.y;                            \
    float sp0 = log2f_fast(1.f + exp2f_fast(s0));                              \
    float sp1 = log2f_fast(1.f + exp2f_fast(s1));                              \
    float sg0 = __builtin_amdgcn_rcpf(1.f + exp2f_fast(-f0));                  \
    float sg1 = __builtin_amdgcn_rcpf(1.f + exp2f_fast(-f1));                  \
    acc.x = fmaf(sp0, sg0, acc.x);                                             \
    acc.y = fmaf(sp1, sg1, acc.y);                                             \
} while (0)

__global__ __launch_bounds__(256, 1) void cg_gather_kernel(
    const unsigned short* __restrict__ P,
    const int* __restrict__ row_ptr,
    const int* __restrict__ csr_src,
    const unsigned int* __restrict__ wE,   // [256][8][4] dwords, thread-major
    const u32x4* __restrict__ eapk,        // [NEDGES][2] fp16-pair attrs, CSR order
    const float* __restrict__ bfv,
    const float* __restrict__ bsv,
    const float* __restrict__ g,
    const float* __restrict__ be,
    const float* __restrict__ xresf,          // fp32 [NNODES,512] or null
    const unsigned short* __restrict__ xresb, // bf16 [NPAD,512] or null
    unsigned short* __restrict__ hout)
{
    const int tid  = threadIdx.x;
    const int lane = tid & 63;
    const int c0  = tid * 2;
    const int nbase = blockIdx.x * CG_NPB;

    // ---- register-resident weight table (asm volatile: cannot rematerialize)
    const unsigned int* wp = wE + (size_t)tid * 32;   // 128 B per thread
    u32x4 w0, w1, w2, w3, w4, w5, w6, w7;
    asm volatile(
        "global_load_dwordx4 %0, %8, off\n\t"
        "global_load_dwordx4 %1, %8, off offset:16\n\t"
        "global_load_dwordx4 %2, %8, off offset:32\n\t"
        "global_load_dwordx4 %3, %8, off offset:48\n\t"
        "global_load_dwordx4 %4, %8, off offset:64\n\t"
        "global_load_dwordx4 %5, %8, off offset:80\n\t"
        "global_load_dwordx4 %6, %8, off offset:96\n\t"
        "global_load_dwordx4 %7, %8, off offset:112\n\t"
        "s_waitcnt vmcnt(0)"
        : "=&v"(w0), "=&v"(w1), "=&v"(w2), "=&v"(w3),
          "=&v"(w4), "=&v"(w5), "=&v"(w6), "=&v"(w7)
        : "v"(wp));
    __builtin_amdgcn_sched_barrier(0);

    const f32x2 bfx = *(const f32x2*)&bfv[c0] * L2E;
    const f32x2 bsx = *(const f32x2*)&bsv[c0] * L2E;
    const f32x2 gv  = *(const f32x2*)&g[c0];
    const f32x2 bev = *(const f32x2*)&be[c0];
    const float rsl = rsqrtf(1.f + 1e-5f) * LN2;   // BN rs * ln2 (base-2 fold)

    for (int n = nbase; n < nbase + CG_NPB; n++) {
        if (n >= NNODES) {
            *(unsigned int*)&hout[(size_t)n * 512 + c0] = 0;
            continue;
        }
        const unsigned short* Pd = P + (size_t)n * 2048;
        const uint2 qb = *(const uint2*)(Pd + c0 * 2);
        const f32x2 baseF = unpack2(qb.x) + bfx;
        const f32x2 baseS = unpack2(qb.y) + bsx;

        f32x2 acc = {0.f, 0.f};
        const int i0 = __builtin_amdgcn_readfirstlane(row_ptr[n]);
        const int i1 = __builtin_amdgcn_readfirstlane(row_ptr[n + 1]);

        for (int base = i0; base < i1; base += 64) {
            const int cnt = min(64, i1 - base);
            int idxc = base + lane;
            if (idxc >= NEDGES) idxc = NEDGES - 1;
            const int sxv = csr_src[idxc];   // one coalesced load: all edge srcs

            uint2 qA = {}, qB = {};
            u32x4 aA0 = {}, aA1 = {}, aB0 = {}, aB1 = {};
            CG_LOADE(qA, aA0, aA1, 0);
            if (cnt > 1) CG_LOADE(qB, aB0, aB1, 1);
            int j = 0;
            while (true) {
                CG_COMP(qA, aA0, aA1);
                if (j + 2 < cnt) CG_LOADE(qA, aA0, aA1, j + 2);
                if (++j >= cnt) break;
                CG_COMP(qB, aB0, aB1);
                if (j + 2 < cnt) CG_LOADE(qB, aB0, aB1, j + 2);
                if (++j >= cnt) break;
            }
        }

        // fused BN(eval) + residual + ReLU  (acc carries log2-form softplus)
        f32x2 res;
        if (xresf) {
            res = *(const f32x2*)&xresf[(size_t)n * 512 + c0];
        } else {
            res = unpack2(*(const unsigned int*)&xresb[(size_t)n * 512 + c0]);
        }
        float v0 = fmaxf(acc.x * (gv.x * rsl) + bev.x + res.x, 0.f);
        float v1 = fmaxf(acc.y * (gv.y * rsl) + bev.y + res.y, 0.f);
        unsigned int packed = (unsigned int)f2b(v0) | ((unsigned int)f2b(v1) << 16);
        *(unsigned int*)&hout[(size_t)n * 512 + c0] = packed;
    }
}

// ---------------- GCN gather (R8 structure, frozen) ----------------
__global__ __launch_bounds__(256) void gcn_gather_kernel(
    const unsigned short* __restrict__ pre,   // bf16 [NPAD,256]
    const int* __restrict__ row_ptr,
    const int* __restrict__ csr_src,
    const float* __restrict__ dinv,
    const float* __restrict__ b,
    unsigned short* __restrict__ hout,  // bf16 [NPAD,256]
    float* __restrict__ doutf)          // fp32 [NNODES,256] or null
{
    const int tid  = threadIdx.x;
    const int lane = tid & 63;
    const int n = blockIdx.x * 4 + (tid >> 6);   // one wave per node
    const int c = lane * 4;                      // 4 channels per thread
    if (n >= NNODES) {
        if (n < NPAD) { uint2 z = {0u, 0u}; *(uint2*)&hout[(size_t)n * 256 + c] = z; }
        return;
    }
    const float din = dinv[n];
    f32x4 acc = {0.f, 0.f, 0.f, 0.f};
    const int i0 = __builtin_amdgcn_readfirstlane(row_ptr[n]);
    const int i1 = __builtin_amdgcn_readfirstlane(row_ptr[n + 1]);

#define GCN_LD(pv_, jj) do {                                                   \
    int sx_ = __builtin_amdgcn_readlane(sxv, (jj));                            \
    pv_ = *(const uint2*)&pre[(size_t)sx_ * 256 + c];                          \
} while (0)

#define GCN_CP(pv_, jj) do {                                                   \
    float dv_ = __builtin_bit_cast(float, __builtin_amdgcn_readlane(dvb, (jj)));\
    f32x2 p0 = unpack2(pv_.x);                                                 \
    f32x2 p1 = unpack2(pv_.y);                                                 \
    acc.x = fmaf(dv_, p0.x, acc.x);                                            \
    acc.y = fmaf(dv_, p0.y, acc.y);                                            \
    acc.z = fmaf(dv_, p1.x, acc.z);                                            \
    acc.w = fmaf(dv_, p1.y, acc.w);                                            \
} while (0)

    for (int base = i0; base < i1; base += 64) {
        const int cnt = min(64, i1 - base);
        int idxc = base + lane;
        if (idxc >= NEDGES) idxc = NEDGES - 1;
        const int sxv = csr_src[idxc];            // all edge srcs, one load
        const int dvb = __builtin_bit_cast(int, dinv[sxv]);  // all dinv, one gather

        uint2 pvA = {}, pvB = {}, pvC = {};
        GCN_LD(pvA, 0);
        if (cnt > 1) GCN_LD(pvB, 1);
        if (cnt > 2) GCN_LD(pvC, 2);
        int j = 0;
        while (true) {
            GCN_CP(pvA, j);
            if (j + 3 < cnt) GCN_LD(pvA, j + 3);
            if (++j >= cnt) break;
            GCN_CP(pvB, j);
            if (j + 3 < cnt) GCN_LD(pvB, j + 3);
            if (++j >= cnt) break;
            GCN_CP(pvC, j);
            if (j + 3 < cnt) GCN_LD(pvC, j + 3);
            if (++j >= cnt) break;
        }
    }
    uint2 sv = *(const uint2*)&pre[(size_t)n * 256 + c];
    f32x2 s0 = unpack2(sv.x);
    f32x2 s1 = unpack2(sv.y);
    const f32x4 bv = *(const f32x4*)&b[c];
    const float d2 = din * din;
    float v0 = fmaxf(fmaf(acc.x, din, d2 * s0.x) + bv.x, 0.f);
    float v1 = fmaxf(fmaf(acc.y, din, d2 * s0.y) + bv.y, 0.f);
    float v2 = fmaxf(fmaf(acc.z, din, d2 * s1.x) + bv.z, 0.f);
    float v3 = fmaxf(fmaf(acc.w, din, d2 * s1.y) + bv.w, 0.f);
    uint2 o;
    o.x = (unsigned int)f2b(v0) | ((unsigned int)f2b(v1) << 16);
    o.y = (unsigned int)f2b(v2) | ((unsigned int)f2b(v3) << 16);
    *(uint2*)&hout[(size_t)n * 256 + c] = o;
    if (doutf) {
        f32x4 vv = {v0, v1, v2, v3};
        *(f32x4*)&doutf[(size_t)n * 256 + c] = vv;
    }
}

// ---------------- MLP ----------------
__global__ void build_zc_kernel(const unsigned short* __restrict__ h4,
                                const float* __restrict__ goal,
                                unsigned short* __restrict__ zc)
{
    long idx = (long)blockIdx.x * blockDim.x + threadIdx.x;
    if (idx >= (long)NPAD * 768) return;
    int n = (int)(idx / 768);
    int c = (int)(idx % 768);
    unsigned short v = 0;
    if (n < NNODES)
        v = (c < 256) ? h4[(size_t)n * 256 + c]
                      : f2b(goal[(size_t)n * 512 + (c - 256)]);
    zc[idx] = v;
}

__global__ __launch_bounds__(256) void final_dot_kernel(
    const unsigned short* __restrict__ t,
    const float* __restrict__ Wd2,
    const float* __restrict__ bd2,
    float* __restrict__ pred)
{
    const int lane = threadIdx.x & 63;
    const int wid  = threadIdx.x >> 6;
    float w[8];
#pragma unroll
    for (int i = 0; i < 8; i++) w[i] = Wd2[lane * 8 + i];
    const float bd = bd2[0];
    for (int n = blockIdx.x * 4 + wid; n < NNODES; n += gridDim.x * 4) {
        const unsigned short* tp = t + (size_t)n * 512 + lane * 8;
        float s = 0.f;
#pragma unroll
        for (int i = 0; i < 8; i++) s = fmaf(b2f(tp[i]), w[i], s);
#pragma unroll
        for (int off = 32; off; off >>= 1) s += __shfl_xor(s, off, 64);
        if (lane == 0) pred[n] = s + bd;
    }
}

// ---------------- launcher ----------------
extern "C" void kernel_launch(void* const* d_in, const int* in_sizes, int n_in,
                              void* d_out, int out_size, void* d_ws, size_t ws_size,
                              hipStream_t stream)
{
    (void)in_sizes; (void)n_in; (void)out_size; (void)ws_size;
    const float* x    = (const float*)d_in[0];
    const int*   ei   = (const int*)d_in[1];
    const float* ea   = (const float*)d_in[2];
    const float* goal = (const float*)d_in[3];
    const float* Wf1  = (const float*)d_in[4];
    const float* bf1  = (const float*)d_in[5];
    const float* Ws1  = (const float*)d_in[6];
    const float* bs1  = (const float*)d_in[7];
    const float* g1   = (const float*)d_in[8];
    const float* be1  = (const float*)d_in[9];
    const float* Wf2  = (const float*)d_in[10];
    const float* bf2  = (const float*)d_in[11];
    const float* Ws2  = (const float*)d_in[12];
    const float* bs2  = (const float*)d_in[13];
    const float* g2   = (const float*)d_in[14];
    const float* be2  = (const float*)d_in[15];
    const float* W3   = (const float*)d_in[16];
    const float* b3   = (const float*)d_in[17];
    const float* W4   = (const float*)d_in[18];
    const float* b4   = (const float*)d_in[19];
    const float* Wd1  = (const float*)d_in[20];
    const float* bd1  = (const float*)d_in[21];
    const float* Wd2  = (const float*)d_in[22];
    const float* bd2  = (const float*)d_in[23];
    float* outp = (float*)d_out;   // fp32: [0..N) pred, [N..N+N*256) h

    char* ws = (char*)d_ws;
    size_t off = 0;
    auto alloc = [&](size_t bytes) -> char* {
        char* p = ws + off;
        off += (bytes + 255) & ~(size_t)255;
        return p;
    };
    unsigned short* P     = (unsigned short*)alloc((size_t)NPAD * 2048 * 2); // later zc + tb
    unsigned short* bufA  = (unsigned short*)alloc((size_t)NPAD * 512 * 2);  // xpad / h2 / h4
    unsigned short* bufB  = (unsigned short*)alloc((size_t)NPAD * 512 * 2);  // h1 / pre_b
    unsigned short* bufC  = (unsigned short*)alloc((size_t)NPAD * 512 * 2);  // h3
    unsigned short* wpack = (unsigned short*)alloc((size_t)2048 * 512 * 2);
    int*            counts  = (int*)alloc((size_t)NNODES * 4);
    int*            row_ptr = (int*)alloc((size_t)(NNODES + 1) * 4);
    int*            csr_src = (int*)alloc((size_t)NEDGES * 4);
    int*            csr_eid = (int*)alloc((size_t)NEDGES * 4);
    float*          dinv    = (float*)alloc((size_t)NNODES * 4);
    unsigned int*   wEbuf   = (unsigned int*)alloc((size_t)8192 * 4);
    unsigned int*   eapk    = (unsigned int*)alloc((size_t)NEDGES * 8 * 4);

    unsigned short* xpad  = bufA;
    unsigned short* h1    = bufB;
    unsigned short* h2    = bufA;
    unsigned short* pre_b = bufB;
    unsigned short* h3    = bufC;
    unsigned short* h4    = bufA;
    unsigned short* zc    = P;
    unsigned short* tb    = P + (size_t)NPAD * 1024;

    const int B = 256;

    // ---- CSR build (by destination) + dinv ----
    hipMemsetAsync(counts, 0, (size_t)NNODES * 4, stream);
    count_kernel<<<(NEDGES + B - 1) / B, B, 0, stream>>>(ei, counts);
    scan_kernel<<<1, 1024, 0, stream>>>(counts, row_ptr);
    hipMemsetAsync(counts, 0, (size_t)NNODES * 4, stream);
    fill_kernel<<<(NEDGES + B - 1) / B, B, 0, stream>>>(ei, row_ptr, counts, csr_src, csr_eid);
    dinv_kernel<<<(NNODES + B - 1) / B, B, 0, stream>>>(row_ptr, dinv);
    pack_ea_kernel<<<(NEDGES * 8 + B - 1) / B, B, 0, stream>>>(csr_eid, ea, eapk);

    {
        long tot = (long)NPAD * 512;
        pad_copy_kernel<<<(unsigned)((tot + B - 1) / B), B, 0, stream>>>(x, xpad, NNODES, 512, tot);
    }

    dim3 gBig(NPAD / 128, 2048 / 128);

    // ---- CGConv layer 1 ----
    pack_cgw_kernel<<<dim3(8, 8, 4), B, 0, stream>>>(Wf1, Ws1, wpack);
    pack_we_kernel<<<(8192 + B - 1) / B, B, 0, stream>>>(Wf1, Ws1, wEbuf);
    gemm_bt_kernel<<<gBig, B, 0, stream>>>(xpad, wpack, nullptr, P, NPAD, 2048, 512, nullptr);
    cg_gather_kernel<<<NPAD / CG_NPB, B, 0, stream>>>(P, row_ptr, csr_src,
                                                      wEbuf, (const u32x4*)eapk,
                                                      bf1, bs1, g1, be1,
                                                      x, nullptr, h1);

    // ---- CGConv layer 2 ----
    pack_cgw_kernel<<<dim3(8, 8, 4), B, 0, stream>>>(Wf2, Ws2, wpack);
    gemm_bt_kernel<<<gBig, B, 0, stream>>>(h1, wpack, nullptr, P, NPAD, 2048, 512, nullptr);
    pack_we_kernel<<<(8192 + B - 1) / B, B, 0, stream>>>(Wf2, Ws2, wEbuf);
    cg_gather_kernel<<<NPAD / CG_NPB, B, 0, stream>>>(P, row_ptr, csr_src,
                                                      wEbuf, (const u32x4*)eapk,
                                                      bf2, bs2, g2, be2,
                                                      nullptr, h1, h2);

    // ---- GCN layer 3 ----
    pack_t_kernel<<<dim3(256 / 64, 512 / 64), B, 0, stream>>>(W3, wpack, 512, 256);
    gemm_bt_kernel<<<dim3(NPAD / 128, 2), B, 0, stream>>>(h2, wpack, nullptr, pre_b, NPAD, 256, 512, nullptr);
    gcn_gather_kernel<<<NPAD / 4, B, 0, stream>>>(pre_b, row_ptr, csr_src, dinv, b3, h3, (float*)nullptr);

    // ---- GCN layer 4 ----
    pack_t_kernel<<<dim3(256 / 64, 256 / 64), B, 0, stream>>>(W4, wpack, 256, 256);
    gemm_bt_kernel<<<dim3(NPAD / 128, 2), B, 0, stream>>>(h3, wpack, nullptr, pre_b, NPAD, 256, 256, nullptr);
    gcn_gather_kernel<<<NPAD / 4, B, 0, stream>>>(pre_b, row_ptr, csr_src, dinv, b4, h4, outp + NNODES);

    // ---- distance MLP (bias+ReLU fused into GEMM epilogue) ----
    build_zc_kernel<<<(unsigned)(((long)NPAD * 768 + B - 1) / B), B, 0, stream>>>(h4, goal, zc);
    pack_t_kernel<<<dim3(512 / 64, 768 / 64), B, 0, stream>>>(Wd1, wpack, 768, 512);
    gemm_bt_kernel<<<dim3(NPAD / 128, 4), B, 0, stream>>>(zc, wpack, nullptr, tb, NPAD, 512, 768, bd1);
    final_dot_kernel<<<512, B, 0, stream>>>(tb, Wd2, bd2, outp);
}

// Round 10
// 730.917 us; speedup vs baseline: 1.1124x; 1.0286x over previous
//
#include <hip/hip_runtime.h>
#include <stdint.h>

#define NNODES 20000
#define NEDGES 160000
#define NPAD   20096   // 157 * 128

typedef float f32x4 __attribute__((ext_vector_type(4)));
typedef float f32x2 __attribute__((ext_vector_type(2)));
typedef short s16x8 __attribute__((ext_vector_type(8)));
typedef unsigned int u32x4 __attribute__((ext_vector_type(4)));
typedef _Float16 h16x2 __attribute__((ext_vector_type(2)));

#define L2E 1.44269504088896340736f
#define LN2 0.6931471805599453f

__device__ __forceinline__ float b2f(unsigned short b) {
    unsigned int u = ((unsigned int)b) << 16;
    return __builtin_bit_cast(float, u);
}
__device__ __forceinline__ unsigned short f2b(float f) {
    unsigned int u = __builtin_bit_cast(unsigned int, f);
    unsigned int r = (u + 0x7FFFu + ((u >> 16) & 1u)) >> 16;
    return (unsigned short)r;
}
// unpack 2 bf16 (packed in a dword) -> float2
__device__ __forceinline__ f32x2 unpack2(unsigned int u) {
    f32x2 r;
    r.x = __builtin_bit_cast(float, u << 16);
    r.y = __builtin_bit_cast(float, u & 0xFFFF0000u);
    return r;
}
// pack two fp32 -> fp16 pair in a dword
__device__ __forceinline__ unsigned int packh2(float a, float b) {
    h16x2 h = { (_Float16)a, (_Float16)b };
    return __builtin_bit_cast(unsigned int, h);
}
// fp16-pair dot with fp32 accumulate: one v_dot2_f32_f16
__device__ __forceinline__ float dot2h(unsigned int a, unsigned int b, float c) {
#if __has_builtin(__builtin_amdgcn_fdot2)
    return __builtin_amdgcn_fdot2(__builtin_bit_cast(h16x2, a),
                                  __builtin_bit_cast(h16x2, b), c, false);
#else
    float d;
    asm("v_dot2_f32_f16 %0, %1, %2, %3" : "=v"(d) : "v"(a), "v"(b), "v"(c));
    return d;
#endif
}
__device__ __forceinline__ float exp2f_fast(float x) {
#if __has_builtin(__builtin_amdgcn_exp2f)
    return __builtin_amdgcn_exp2f(x);
#else
    return __builtin_exp2f(x);
#endif
}
__device__ __forceinline__ float log2f_fast(float x) {
#if __has_builtin(__builtin_amdgcn_logf)
    return __builtin_amdgcn_logf(x);
#else
    return __builtin_log2f(x);
#endif
}

// ---- GEMM: C[M,N] = A[M,K](bf16) @ BT[N,K]^T(bf16); C fp32 or bf16 ----
// BK=64 + XOR bank-conflict swizzle + XCD-aware bijective block swizzle.
__global__ __launch_bounds__(256) void gemm_bt_kernel(
    const unsigned short* __restrict__ A,
    const unsigned short* __restrict__ BT,
    float* __restrict__ Cf,
    unsigned short* __restrict__ Cb,
    int M, int N, int K,
    const float* __restrict__ bias)
{
    __shared__ unsigned short As[128 * 64];
    __shared__ unsigned short Bs[128 * 64];
    const int tid  = threadIdx.x;
    const int wid  = tid >> 6;
    const int lane = tid & 63;

    // ---- XCD-aware bijective swizzle of the flat block id
    const int nwg  = gridDim.x * gridDim.y;
    const int orig = blockIdx.y * gridDim.x + blockIdx.x;  // dispatch order (x fastest)
    const int q = nwg >> 3, r = nwg & 7;
    const int xcd = orig & 7;
    const int idx = orig >> 3;
    const int swz = (xcd < r ? xcd * (q + 1) : r * (q + 1) + (xcd - r) * q) + idx;
    const int bm = (swz / gridDim.y) * 128;
    const int bn = (swz % gridDim.y) * 128;

    const int wm = (wid & 1) * 64;
    const int wn = (wid >> 1) * 64;

    f32x4 acc[4][4];
#pragma unroll
    for (int i = 0; i < 4; i++)
#pragma unroll
        for (int j = 0; j < 4; j++) acc[i][j] = {0.f, 0.f, 0.f, 0.f};

    for (int k0 = 0; k0 < K; k0 += 64) {
#pragma unroll
        for (int rr = 0; rr < 4; rr++) {
            int flat = rr * 256 + tid;      // 0..1023
            int row  = flat >> 3;           // 128 rows
            int part = flat & 7;            // 8 x 16B chunks per row
            int pg   = part ^ (row & 7);    // pre-swizzled global chunk
            const unsigned short* ga = A  + (size_t)(bm + row) * K + k0 + pg * 8;
            const unsigned short* gb = BT + (size_t)(bn + row) * K + k0 + pg * 8;
            __builtin_amdgcn_global_load_lds(
                (const __attribute__((address_space(1))) unsigned int*)ga,
                (__attribute__((address_space(3))) unsigned int*)&As[flat * 8], 16, 0, 0);
            __builtin_amdgcn_global_load_lds(
                (const __attribute__((address_space(1))) unsigned int*)gb,
                (__attribute__((address_space(3))) unsigned int*)&Bs[flat * 8], 16, 0, 0);
        }
        __syncthreads();

        const int kq8 = lane >> 4;     // 0..3
        const int rl  = lane & 15;
#pragma unroll
        for (int kk = 0; kk < 2; kk++) {
            s16x8 af[4], bfr[4];
#pragma unroll
            for (int mi = 0; mi < 4; mi++) {
                int row = wm + mi * 16 + rl;
                int slot = (kk * 4 + kq8) ^ (row & 7);
                af[mi] = *(const s16x8*)&As[row * 64 + slot * 8];
            }
#pragma unroll
            for (int ni = 0; ni < 4; ni++) {
                int row = wn + ni * 16 + rl;
                int slot = (kk * 4 + kq8) ^ (row & 7);
                bfr[ni] = *(const s16x8*)&Bs[row * 64 + slot * 8];
            }
#pragma unroll
            for (int mi = 0; mi < 4; mi++)
#pragma unroll
                for (int ni = 0; ni < 4; ni++)
                    acc[mi][ni] = __builtin_amdgcn_mfma_f32_16x16x32_bf16(
                        af[mi], bfr[ni], acc[mi][ni], 0, 0, 0);
        }
        __syncthreads();
    }

    const int cl = lane & 15;
    const int rq = (lane >> 4) * 4;
#pragma unroll
    for (int mi = 0; mi < 4; mi++)
#pragma unroll
        for (int ni = 0; ni < 4; ni++)
#pragma unroll
            for (int rr = 0; rr < 4; rr++) {
                int row = bm + wm + mi * 16 + rq + rr;
                int col = bn + wn + ni * 16 + cl;
                float v = acc[mi][ni][rr];
                if (Cb) {
                    if (bias) v = fmaxf(v + bias[col], 0.f);
                    Cb[(size_t)row * N + col] = f2b(v);
                } else {
                    Cf[(size_t)row * N + col] = v;
                }
            }
}

// ---------------- CSR build ----------------
__global__ void count_kernel(const int* __restrict__ ei, int* __restrict__ counts) {
    int e = blockIdx.x * blockDim.x + threadIdx.x;
    if (e < NEDGES) atomicAdd(&counts[ei[NEDGES + e]], 1);
}

__global__ __launch_bounds__(1024) void scan_kernel(const int* __restrict__ counts,
                                                    int* __restrict__ row_ptr)
{
    __shared__ int sdata[1024];
    const int t = threadIdx.x;
    int vals[20];
    const int base = t * 20;
    int lsum = 0;
#pragma unroll
    for (int j = 0; j < 20; j++) {
        int idx = base + j;
        int v = (idx < NNODES) ? counts[idx] : 0;
        vals[j] = v; lsum += v;
    }
    sdata[t] = lsum;
    __syncthreads();
    for (int off = 1; off < 1024; off <<= 1) {
        int v = (t >= off) ? sdata[t - off] : 0;
        __syncthreads();
        sdata[t] += v;
        __syncthreads();
    }
    int run = sdata[t] - lsum;
#pragma unroll
    for (int j = 0; j < 20; j++) {
        int idx = base + j;
        if (idx < NNODES) row_ptr[idx] = run;
        run += vals[j];
    }
    if (t == 1023) row_ptr[NNODES] = sdata[1023];
}

__global__ void fill_kernel(const int* __restrict__ ei,
                            const int* __restrict__ row_ptr,
                            int* __restrict__ cursor,
                            int* __restrict__ csr_src,
                            int* __restrict__ csr_eid)
{
    int e = blockIdx.x * blockDim.x + threadIdx.x;
    if (e >= NEDGES) return;
    int dst = ei[NEDGES + e];
    int p = row_ptr[dst] + atomicAdd(&cursor[dst], 1);
    csr_src[p] = ei[e];
    csr_eid[p] = e;
}

__global__ void dinv_kernel(const int* __restrict__ row_ptr, float* __restrict__ dinv) {
    int i = blockIdx.x * blockDim.x + threadIdx.x;
    if (i < NNODES) {
        int deg = row_ptr[i + 1] - row_ptr[i] + 1;   // + self loop
        dinv[i] = rsqrtf((float)deg);
    }
}

// ---------------- packing ----------------
// vectorized x8 pad+convert: one uint4 (8 bf16) per thread
__global__ void pad_copy_kernel(const float* __restrict__ src,
                                unsigned short* __restrict__ dst,
                                long total8)
{
    long idx = (long)blockIdx.x * blockDim.x + threadIdx.x;
    if (idx >= total8) return;
    int n  = (int)(idx >> 6);
    int c8 = ((int)idx & 63) * 8;
    uint4 o = {0u, 0u, 0u, 0u};
    if (n < NNODES) {
        const float* sp = src + (size_t)n * 512 + c8;
        f32x4 a = *(const f32x4*)sp;
        f32x4 b = *(const f32x4*)(sp + 4);
        o.x = (unsigned)f2b(a.x) | ((unsigned)f2b(a.y) << 16);
        o.y = (unsigned)f2b(a.z) | ((unsigned)f2b(a.w) << 16);
        o.z = (unsigned)f2b(b.x) | ((unsigned)f2b(b.y) << 16);
        o.w = (unsigned)f2b(b.z) | ((unsigned)f2b(b.w) << 16);
    }
    *(uint4*)&dst[(size_t)n * 512 + c8] = o;
}

// LDS-tiled TRANSPOSING pack for CGConv GEMM weights (values pre-scaled L2E)
__global__ __launch_bounds__(256) void pack_cgw_kernel(
    const float* __restrict__ Wf,
    const float* __restrict__ Ws,
    unsigned short* __restrict__ out)
{
    __shared__ float tile[64][65];
    const int tx  = threadIdx.x & 63;
    const int ty4 = threadIdx.x >> 6;
    const int c0 = blockIdx.x * 64;
    const int k0 = blockIdx.y * 64;
    const int fs   = blockIdx.z & 1;
    const int half = blockIdx.z >> 1;
    const float* W = fs ? Ws : Wf;
    const float* Wb = W + (size_t)(half ? 512 : 0) * 512;
    for (int rr = ty4; rr < 64; rr += 4)
        tile[rr][tx] = Wb[(size_t)(k0 + rr) * 512 + (c0 + tx)];
    __syncthreads();
    for (int rr = ty4; rr < 64; rr += 4) {
        int c = c0 + rr;
        int j = half * 1024 + (c >> 1) * 4 + fs * 2 + (c & 1);
        out[(size_t)j * 512 + (k0 + tx)] = f2b(tile[tx][rr] * L2E);
    }
}

// LDS-tiled transpose pack: WT[j*K+k] = W[k*Nout+j].
__global__ __launch_bounds__(256) void pack_t_kernel(
    const float* __restrict__ W,
    unsigned short* __restrict__ WT,
    int K, int Nout)
{
    __shared__ float tile[64][65];
    const int tx  = threadIdx.x & 63;
    const int ty4 = threadIdx.x >> 6;
    const int j0 = blockIdx.x * 64;
    const int k0 = blockIdx.y * 64;
    for (int rr = ty4; rr < 64; rr += 4)
        tile[rr][tx] = W[(size_t)(k0 + rr) * Nout + (j0 + tx)];
    __syncthreads();
    for (int rr = ty4; rr < 64; rr += 4)
        WT[(size_t)(j0 + rr) * K + (k0 + tx)] = f2b(tile[tx][rr]);
}

// W_e table, THREAD-MAJOR: dword idx = tid*32 + k*4 + q (128 B/thread).
__global__ void pack_we_kernel(const float* __restrict__ Wf,
                               const float* __restrict__ Ws,
                               unsigned int* __restrict__ out)
{
    int idx = blockIdx.x * blockDim.x + threadIdx.x;
    if (idx >= 8192) return;
    int tid = idx >> 5;
    int r   = idx & 31;
    int k   = r >> 2;
    int q   = r & 3;
    const float* W = (q >> 1) ? Ws : Wf;
    int c = tid * 2 + (q & 1);
    float v0 = W[(size_t)(1024 + 2 * k) * 512 + c] * L2E;
    float v1 = W[(size_t)(1024 + 2 * k + 1) * 512 + c] * L2E;
    out[idx] = packh2(v0, v1);
}

// edge attrs as fp16 pairs in CSR order
__global__ void pack_ea_kernel(const int* __restrict__ csr_eid,
                               const float* __restrict__ ea,
                               unsigned int* __restrict__ out)
{
    int idx = blockIdx.x * blockDim.x + threadIdx.x;
    if (idx >= NEDGES * 8) return;
    int i = idx >> 3;
    int j = idx & 7;
    int eid = csr_eid[i];
    out[idx] = packh2(ea[(size_t)eid * 16 + 2 * j], ea[(size_t)eid * 16 + 2 * j + 1]);
}

// ---------------- CGConv gather: block-level EDGE STREAM ----------------
// R10: nodes in a block have CONTIGUOUS CSR ranges -> stream all their edges
// through ONE depth-2 pipeline; finalize nodes inline at (scalar, uniform)
// boundaries with next-node state prefetched. Eliminates the per-node pipeline
// drain (avg deg 8 -> drains were ~1/3 of runtime). Control flow is wave-
// uniform: boundaries come from readlane of a lane-held row_ptr slice.
#define CG_NPB 8

#define CG_LOADE(q_, a0_, a1_, jj) do {                                        \
    int sx_ = __builtin_amdgcn_readlane(sxv, (jj));                            \
    q_  = *(const uint2*)(P + (size_t)sx_ * 2048 + 1024 + c0 * 2);             \
    a0_ = eapk[(size_t)(base + (jj)) * 2];                                     \
    a1_ = eapk[(size_t)(base + (jj)) * 2 + 1];                                 \
} while (0)

#define CG_COMP(q_, a0_, a1_) do {                                             \
    float f0 = baseF.x, f1 = baseF.y, s0 = baseS.x, s1 = baseS.y;              \
    f0 = dot2h(a0_[0], w0[0], f0); f1 = dot2h(a0_[0], w0[1], f1);              \
    s0 = dot2h(a0_[0], w0[2], s0); s1 = dot2h(a0_[0], w0[3], s1);              \
    f0 = dot2h(a0_[1], w1[0], f0); f1 = dot2h(a0_[1], w1[1], f1);              \
    s0 = dot2h(a0_[1], w1[2], s0); s1 = dot2h(a0_[1], w1[3], s1);              \
    f0 = dot2h(a0_[2], w2[0], f0); f1 = dot2h(a0_[2], w2[1], f1);              \
    s0 = dot2h(a0_[2], w2[2], s0); s1 = dot2h(a0_[2], w2[3], s1);              \
    f0 = dot2h(a0_[3], w3[0], f0); f1 = dot2h(a0_[3], w3[1], f1);              \
    s0 = dot2h(a0_[3], w3[2], s0); s1 = dot2h(a0_[3], w3[3], s1);              \
    f0 = dot2h(a1_[0], w4[0], f0); f1 = dot2h(a1_[0], w4[1], f1);              \
    s0 = dot2h(a1_[0], w4[2], s0); s1 = dot2h(a1_[0], w4[3], s1);              \
    f0 = dot2h(a1_[1], w5[0], f0); f1 = dot2h(a1_[1], w5[1], f1);              \
    s0 = dot2h(a1_[1], w5[2], s0); s1 = dot2h(a1_[1], w5[3], s1);              \
    f0 = dot2h(a1_[2], w6[0], f0); f1 = dot2h(a1_[2], w6[1], f1);              \
    s0 = dot2h(a1_[2], w6[2], s0); s1 = dot2h(a1_[2], w6[3], s1);              \
    f0 = dot2h(a1_[3], w7[0], f0); f1 = dot2h(a1_[3], w7[1], f1);              \
    s0 = dot2h(a1_[3], w7[2], s0); s1 = dot2h(a1_[3], w7[3], s1);              \
    f32x2 pf = unpack2(q_.x);                                                  \
    f32x2 ps = unpack2(q_.y);                                                  \
    f0 += pf.x; f1 += pf.y; s0 += ps.x; s1 += ps.y;                            \
    float sp0 = log2f_fast(1.f + exp2f_fast(s0));                              \
    float sp1 = log2f_fast(1.f + exp2f_fast(s1));                              \
    float sg0 = __builtin_amdgcn_rcpf(1.f + exp2f_fast(-f0));                  \
    float sg1 = __builtin_amdgcn_rcpf(1.f + exp2f_fast(-f1));                  \
    acc.x = fmaf(sp0, sg0, acc.x);                                             \
    acc.y = fmaf(sp1, sg1, acc.y);                                             \
} while (0)

// finalize node slot `cur`, rotate to prefetched next-node state
#define CG_FINAL() do {                                                        \
    int nn_ = nbase + cur;                                                     \
    unsigned int packed_ = 0u;                                                 \
    if (nn_ < NNODES) {                                                        \
        float v0_ = fmaxf(acc.x * (gv.x * rsl) + bev.x + resC.x, 0.f);         \
        float v1_ = fmaxf(acc.y * (gv.y * rsl) + bev.y + resC.y, 0.f);         \
        packed_ = (unsigned int)f2b(v0_) | ((unsigned int)f2b(v1_) << 16);     \
    }                                                                          \
    *(unsigned int*)&hout[(size_t)nn_ * 512 + c0] = packed_;                   \
    cur++;                                                                     \
    qbC = qbN; resC = resN;                                                    \
    if (cur + 1 < CG_NPB) { qbN = loadQB(cur + 1); resN = loadRes(cur + 1); }  \
    baseF = unpack2(qbC.x) + bfx;                                              \
    baseS = unpack2(qbC.y) + bsx;                                              \
    acc.x = 0.f; acc.y = 0.f;                                                  \
    bnd = __builtin_amdgcn_readlane(rpl, cur + 1 < CG_NPB ? cur + 1 : CG_NPB); \
} while (0)

__global__ __launch_bounds__(256, 1) void cg_gather_kernel(
    const unsigned short* __restrict__ P,
    const int* __restrict__ row_ptr,
    const int* __restrict__ csr_src,
    const unsigned int* __restrict__ wE,   // [256][8][4] dwords, thread-major
    const u32x4* __restrict__ eapk,        // [NEDGES][2] fp16-pair attrs, CSR order
    const float* __restrict__ bfv,
    const float* __restrict__ bsv,
    const float* __restrict__ g,
    const float* __restrict__ be,
    const float* __restrict__ xresf,          // fp32 [NNODES,512] or null
    const unsigned short* __restrict__ xresb, // bf16 [NPAD,512] or null
    unsigned short* __restrict__ hout)
{
    const int tid  = threadIdx.x;
    const int lane = tid & 63;
    const int c0  = tid * 2;
    const int nbase = blockIdx.x * CG_NPB;

    // ---- register-resident weight table (asm volatile: cannot rematerialize)
    const unsigned int* wp = wE + (size_t)tid * 32;   // 128 B per thread
    u32x4 w0, w1, w2, w3, w4, w5, w6, w7;
    asm volatile(
        "global_load_dwordx4 %0, %8, off\n\t"
        "global_load_dwordx4 %1, %8, off offset:16\n\t"
        "global_load_dwordx4 %2, %8, off offset:32\n\t"
        "global_load_dwordx4 %3, %8, off offset:48\n\t"
        "global_load_dwordx4 %4, %8, off offset:64\n\t"
        "global_load_dwordx4 %5, %8, off offset:80\n\t"
        "global_load_dwordx4 %6, %8, off offset:96\n\t"
        "global_load_dwordx4 %7, %8, off offset:112\n\t"
        "s_waitcnt vmcnt(0)"
        : "=&v"(w0), "=&v"(w1), "=&v"(w2), "=&v"(w3),
          "=&v"(w4), "=&v"(w5), "=&v"(w6), "=&v"(w7)
        : "v"(wp));
    __builtin_amdgcn_sched_barrier(0);

    const f32x2 bfx = *(const f32x2*)&bfv[c0] * L2E;
    const f32x2 bsx = *(const f32x2*)&bsv[c0] * L2E;
    const f32x2 gv  = *(const f32x2*)&g[c0];
    const f32x2 bev = *(const f32x2*)&be[c0];
    const float rsl = rsqrtf(1.f + 1e-5f) * LN2;   // BN rs * ln2 (base-2 fold)

    // row_ptr[nbase .. nbase+NPB] held across lanes 0..NPB
    int rpidx = nbase + (lane < CG_NPB ? lane : CG_NPB);
    if (rpidx > NNODES) rpidx = NNODES;
    const int rpl = row_ptr[rpidx];
    const int e0 = __builtin_amdgcn_readlane(rpl, 0);
    const int e1 = __builtin_amdgcn_readlane(rpl, CG_NPB);

    // per-node prefetched state
    auto loadQB = [&](int s) -> uint2 {
        int nn = nbase + s;
        if (nn >= NNODES) { uint2 z = {0u, 0u}; return z; }
        return *(const uint2*)(P + (size_t)nn * 2048 + c0 * 2);
    };
    auto loadRes = [&](int s) -> f32x2 {
        int nn = nbase + s;
        f32x2 z = {0.f, 0.f};
        if (nn >= NNODES) return z;
        if (xresf) return *(const f32x2*)&xresf[(size_t)nn * 512 + c0];
        return unpack2(*(const unsigned int*)&xresb[(size_t)nn * 512 + c0]);
    };

    int cur = 0;
    uint2 qbC = loadQB(0);
    f32x2 resC = loadRes(0);
    uint2 qbN = loadQB(1);
    f32x2 resN = loadRes(1);
    f32x2 baseF = unpack2(qbC.x) + bfx;
    f32x2 baseS = unpack2(qbC.y) + bsx;
    f32x2 acc = {0.f, 0.f};
    int bnd = __builtin_amdgcn_readlane(rpl, 1);

    // ---- continuous edge stream over all CG_NPB nodes' edges
    for (int base = e0; base < e1; base += 64) {
        const int cnt = min(64, e1 - base);
        int idxc = base + lane;
        if (idxc >= NEDGES) idxc = NEDGES - 1;
        const int sxv = csr_src[idxc];   // one coalesced load: 64 edge srcs

        uint2 qA = {}, qB = {};
        u32x4 aA0 = {}, aA1 = {}, aB0 = {}, aB1 = {};
        CG_LOADE(qA, aA0, aA1, 0);
        if (cnt > 1) CG_LOADE(qB, aB0, aB1, 1);
        int j = 0;
        while (true) {
            while (base + j >= bnd) CG_FINAL();
            CG_COMP(qA, aA0, aA1);
            if (j + 2 < cnt) CG_LOADE(qA, aA0, aA1, j + 2);
            if (++j >= cnt) break;
            while (base + j >= bnd) CG_FINAL();
            CG_COMP(qB, aB0, aB1);
            if (j + 2 < cnt) CG_LOADE(qB, aB0, aB1, j + 2);
            if (++j >= cnt) break;
        }
    }
    // drain remaining nodes (zero-degree tails / padding)
    while (cur < CG_NPB) CG_FINAL();
}

// ---------------- GCN gather (R8 structure, frozen) ----------------
__global__ __launch_bounds__(256) void gcn_gather_kernel(
    const unsigned short* __restrict__ pre,   // bf16 [NPAD,256]
    const int* __restrict__ row_ptr,
    const int* __restrict__ csr_src,
    const float* __restrict__ dinv,
    const float* __restrict__ b,
    unsigned short* __restrict__ hout,  // bf16 [NPAD,256]
    float* __restrict__ doutf)          // fp32 [NNODES,256] or null
{
    const int tid  = threadIdx.x;
    const int lane = tid & 63;
    const int n = blockIdx.x * 4 + (tid >> 6);   // one wave per node
    const int c = lane * 4;                      // 4 channels per thread
    if (n >= NNODES) {
        if (n < NPAD) { uint2 z = {0u, 0u}; *(uint2*)&hout[(size_t)n * 256 + c] = z; }
        return;
    }
    const float din = dinv[n];
    f32x4 acc = {0.f, 0.f, 0.f, 0.f};
    const int i0 = __builtin_amdgcn_readfirstlane(row_ptr[n]);
    const int i1 = __builtin_amdgcn_readfirstlane(row_ptr[n + 1]);

#define GCN_LD(pv_, jj) do {                                                   \
    int sx_ = __builtin_amdgcn_readlane(sxv, (jj));                            \
    pv_ = *(const uint2*)&pre[(size_t)sx_ * 256 + c];                          \
} while (0)

#define GCN_CP(pv_, jj) do {                                                   \
    float dv_ = __builtin_bit_cast(float, __builtin_amdgcn_readlane(dvb, (jj)));\
    f32x2 p0 = unpack2(pv_.x);                                                 \
    f32x2 p1 = unpack2(pv_.y);                                                 \
    acc.x = fmaf(dv_, p0.x, acc.x);                                            \
    acc.y = fmaf(dv_, p0.y, acc.y);                                            \
    acc.z = fmaf(dv_, p1.x, acc.z);                                            \
    acc.w = fmaf(dv_, p1.y, acc.w);                                            \
} while (0)

    for (int base = i0; base < i1; base += 64) {
        const int cnt = min(64, i1 - base);
        int idxc = base + lane;
        if (idxc >= NEDGES) idxc = NEDGES - 1;
        const int sxv = csr_src[idxc];            // all edge srcs, one load
        const int dvb = __builtin_bit_cast(int, dinv[sxv]);  // all dinv, one gather

        uint2 pvA = {}, pvB = {}, pvC = {};
        GCN_LD(pvA, 0);
        if (cnt > 1) GCN_LD(pvB, 1);
        if (cnt > 2) GCN_LD(pvC, 2);
        int j = 0;
        while (true) {
            GCN_CP(pvA, j);
            if (j + 3 < cnt) GCN_LD(pvA, j + 3);
            if (++j >= cnt) break;
            GCN_CP(pvB, j);
            if (j + 3 < cnt) GCN_LD(pvB, j + 3);
            if (++j >= cnt) break;
            GCN_CP(pvC, j);
            if (j + 3 < cnt) GCN_LD(pvC, j + 3);
            if (++j >= cnt) break;
        }
    }
    uint2 sv = *(const uint2*)&pre[(size_t)n * 256 + c];
    f32x2 s0 = unpack2(sv.x);
    f32x2 s1 = unpack2(sv.y);
    const f32x4 bv = *(const f32x4*)&b[c];
    const float d2 = din * din;
    float v0 = fmaxf(fmaf(acc.x, din, d2 * s0.x) + bv.x, 0.f);
    float v1 = fmaxf(fmaf(acc.y, din, d2 * s0.y) + bv.y, 0.f);
    float v2 = fmaxf(fmaf(acc.z, din, d2 * s1.x) + bv.z, 0.f);
    float v3 = fmaxf(fmaf(acc.w, din, d2 * s1.y) + bv.w, 0.f);
    uint2 o;
    o.x = (unsigned int)f2b(v0) | ((unsigned int)f2b(v1) << 16);
    o.y = (unsigned int)f2b(v2) | ((unsigned int)f2b(v3) << 16);
    *(uint2*)&hout[(size_t)n * 256 + c] = o;
    if (doutf) {
        f32x4 vv = {v0, v1, v2, v3};
        *(f32x4*)&doutf[(size_t)n * 256 + c] = vv;
    }
}

// ---------------- MLP ----------------
// zc[:, 0:256] = h4 (bf16 copy, vector; shift-indexed -- no div)
__global__ void zc_h4_kernel(const unsigned short* __restrict__ h4,
                             unsigned short* __restrict__ zc)
{
    int idx = blockIdx.x * blockDim.x + threadIdx.x;   // NPAD*32
    if (idx >= NPAD * 32) return;
    int n  = idx >> 5;
    int c8 = (idx & 31) * 8;
    uint4 v = {0u, 0u, 0u, 0u};
    if (n < NNODES) v = *(const uint4*)&h4[(size_t)n * 256 + c8];
    *(uint4*)&zc[(size_t)n * 768 + c8] = v;
}

// zc[:, 256:768] = f2b(goal) (vector; shift-indexed)
__global__ void zc_goal_kernel(const float* __restrict__ goal,
                               unsigned short* __restrict__ zc)
{
    int idx = blockIdx.x * blockDim.x + threadIdx.x;   // NPAD*64
    if (idx >= NPAD * 64) return;
    int n  = idx >> 6;
    int c8 = (idx & 63) * 8;
    uint4 o = {0u, 0u, 0u, 0u};
    if (n < NNODES) {
        const float* sp = goal + (size_t)n * 512 + c8;
        f32x4 a = *(const f32x4*)sp;
        f32x4 b = *(const f32x4*)(sp + 4);
        o.x = (unsigned)f2b(a.x) | ((unsigned)f2b(a.y) << 16);
        o.y = (unsigned)f2b(a.z) | ((unsigned)f2b(a.w) << 16);
        o.z = (unsigned)f2b(b.x) | ((unsigned)f2b(b.y) << 16);
        o.w = (unsigned)f2b(b.z) | ((unsigned)f2b(b.w) << 16);
    }
    *(uint4*)&zc[(size_t)n * 768 + 256 + c8] = o;
}

__global__ __launch_bounds__(256) void final_dot_kernel(
    const unsigned short* __restrict__ t,
    const float* __restrict__ Wd2,
    const float* __restrict__ bd2,
    float* __restrict__ pred)
{
    const int lane = threadIdx.x & 63;
    const int wid  = threadIdx.x >> 6;
    float w[8];
#pragma unroll
    for (int i = 0; i < 8; i++) w[i] = Wd2[lane * 8 + i];
    const float bd = bd2[0];
    for (int n = blockIdx.x * 4 + wid; n < NNODES; n += gridDim.x * 4) {
        const unsigned short* tp = t + (size_t)n * 512 + lane * 8;
        float s = 0.f;
#pragma unroll
        for (int i = 0; i < 8; i++) s = fmaf(b2f(tp[i]), w[i], s);
#pragma unroll
        for (int off = 32; off; off >>= 1) s += __shfl_xor(s, off, 64);
        if (lane == 0) pred[n] = s + bd;
    }
}

// ---------------- launcher ----------------
extern "C" void kernel_launch(void* const* d_in, const int* in_sizes, int n_in,
                              void* d_out, int out_size, void* d_ws, size_t ws_size,
                              hipStream_t stream)
{
    (void)in_sizes; (void)n_in; (void)out_size; (void)ws_size;
    const float* x    = (const float*)d_in[0];
    const int*   ei   = (const int*)d_in[1];
    const float* ea   = (const float*)d_in[2];
    const float* goal = (const float*)d_in[3];
    const float* Wf1  = (const float*)d_in[4];
    const float* bf1  = (const float*)d_in[5];
    const float* Ws1  = (const float*)d_in[6];
    const float* bs1  = (const float*)d_in[7];
    const float* g1   = (const float*)d_in[8];
    const float* be1  = (const float*)d_in[9];
    const float* Wf2  = (const float*)d_in[10];
    const float* bf2  = (const float*)d_in[11];
    const float* Ws2  = (const float*)d_in[12];
    const float* bs2  = (const float*)d_in[13];
    const float* g2   = (const float*)d_in[14];
    const float* be2  = (const float*)d_in[15];
    const float* W3   = (const float*)d_in[16];
    const float* b3   = (const float*)d_in[17];
    const float* W4   = (const float*)d_in[18];
    const float* b4   = (const float*)d_in[19];
    const float* Wd1  = (const float*)d_in[20];
    const float* bd1  = (const float*)d_in[21];
    const float* Wd2  = (const float*)d_in[22];
    const float* bd2  = (const float*)d_in[23];
    float* outp = (float*)d_out;   // fp32: [0..N) pred, [N..N+N*256) h

    char* ws = (char*)d_ws;
    size_t off = 0;
    auto alloc = [&](size_t bytes) -> char* {
        char* p = ws + off;
        off += (bytes + 255) & ~(size_t)255;
        return p;
    };
    unsigned short* P     = (unsigned short*)alloc((size_t)NPAD * 2048 * 2); // later zc + tb
    unsigned short* bufA  = (unsigned short*)alloc((size_t)NPAD * 512 * 2);  // xpad / h2 / h4
    unsigned short* bufB  = (unsigned short*)alloc((size_t)NPAD * 512 * 2);  // h1 / pre_b
    unsigned short* bufC  = (unsigned short*)alloc((size_t)NPAD * 512 * 2);  // h3
    unsigned short* wpack = (unsigned short*)alloc((size_t)2048 * 512 * 2);
    int*            counts  = (int*)alloc((size_t)NNODES * 4);
    int*            row_ptr = (int*)alloc((size_t)(NNODES + 1) * 4);
    int*            csr_src = (int*)alloc((size_t)NEDGES * 4);
    int*            csr_eid = (int*)alloc((size_t)NEDGES * 4);
    float*          dinv    = (float*)alloc((size_t)NNODES * 4);
    unsigned int*   wEbuf   = (unsigned int*)alloc((size_t)8192 * 4);
    unsigned int*   eapk    = (unsigned int*)alloc((size_t)NEDGES * 8 * 4);

    unsigned short* xpad  = bufA;
    unsigned short* h1    = bufB;
    unsigned short* h2    = bufA;
    unsigned short* pre_b = bufB;
    unsigned short* h3    = bufC;
    unsigned short* h4    = bufA;
    unsigned short* zc    = P;
    unsigned short* tb    = P + (size_t)NPAD * 1024;

    const int B = 256;

    // ---- CSR build (by destination) + dinv ----
    hipMemsetAsync(counts, 0, (size_t)NNODES * 4, stream);
    count_kernel<<<(NEDGES + B - 1) / B, B, 0, stream>>>(ei, counts);
    scan_kernel<<<1, 1024, 0, stream>>>(counts, row_ptr);
    hipMemsetAsync(counts, 0, (size_t)NNODES * 4, stream);
    fill_kernel<<<(NEDGES + B - 1) / B, B, 0, stream>>>(ei, row_ptr, counts, csr_src, csr_eid);
    dinv_kernel<<<(NNODES + B - 1) / B, B, 0, stream>>>(row_ptr, dinv);
    pack_ea_kernel<<<(NEDGES * 8 + B - 1) / B, B, 0, stream>>>(csr_eid, ea, eapk);

    {
        long tot8 = (long)NPAD * 64;
        pad_copy_kernel<<<(unsigned)((tot8 + B - 1) / B), B, 0, stream>>>(x, xpad, tot8);
    }

    dim3 gBig(NPAD / 128, 2048 / 128);

    // ---- CGConv layer 1 ----
    pack_cgw_kernel<<<dim3(8, 8, 4), B, 0, stream>>>(Wf1, Ws1, wpack);
    pack_we_kernel<<<(8192 + B - 1) / B, B, 0, stream>>>(Wf1, Ws1, wEbuf);
    gemm_bt_kernel<<<gBig, B, 0, stream>>>(xpad, wpack, nullptr, P, NPAD, 2048, 512, nullptr);
    cg_gather_kernel<<<NPAD / CG_NPB, B, 0, stream>>>(P, row_ptr, csr_src,
                                                      wEbuf, (const u32x4*)eapk,
                                                      bf1, bs1, g1, be1,
                                                      x, nullptr, h1);

    // ---- CGConv layer 2 ----
    pack_cgw_kernel<<<dim3(8, 8, 4), B, 0, stream>>>(Wf2, Ws2, wpack);
    gemm_bt_kernel<<<gBig, B, 0, stream>>>(h1, wpack, nullptr, P, NPAD, 2048, 512, nullptr);
    pack_we_kernel<<<(8192 + B - 1) / B, B, 0, stream>>>(Wf2, Ws2, wEbuf);
    cg_gather_kernel<<<NPAD / CG_NPB, B, 0, stream>>>(P, row_ptr, csr_src,
                                                      wEbuf, (const u32x4*)eapk,
                                                      bf2, bs2, g2, be2,
                                                      nullptr, h1, h2);

    // ---- GCN layer 3 ----
    pack_t_kernel<<<dim3(256 / 64, 512 / 64), B, 0, stream>>>(W3, wpack, 512, 256);
    gemm_bt_kernel<<<dim3(NPAD / 128, 2), B, 0, stream>>>(h2, wpack, nullptr, pre_b, NPAD, 256, 512, nullptr);
    gcn_gather_kernel<<<NPAD / 4, B, 0, stream>>>(pre_b, row_ptr, csr_src, dinv, b3, h3, (float*)nullptr);

    // ---- GCN layer 4 ----
    pack_t_kernel<<<dim3(256 / 64, 256 / 64), B, 0, stream>>>(W4, wpack, 256, 256);
    gemm_bt_kernel<<<dim3(NPAD / 128, 2), B, 0, stream>>>(h3, wpack, nullptr, pre_b, NPAD, 256, 256, nullptr);
    gcn_gather_kernel<<<NPAD / 4, B, 0, stream>>>(pre_b, row_ptr, csr_src, dinv, b4, h4, outp + NNODES);

    // ---- distance MLP (bias+ReLU fused into GEMM epilogue) ----
    zc_h4_kernel<<<(NPAD * 32 + B - 1) / B, B, 0, stream>>>(h4, zc);
    zc_goal_kernel<<<(NPAD * 64 + B - 1) / B, B, 0, stream>>>(goal, zc);
    pack_t_kernel<<<dim3(512 / 64, 768 / 64), B, 0, stream>>>(Wd1, wpack, 768, 512);
    gemm_bt_kernel<<<dim3(NPAD / 128, 4), B, 0, stream>>>(zc, wpack, nullptr, tb, NPAD, 512, 768, bd1);
    final_dot_kernel<<<512, B, 0, stream>>>(tb, Wd2, bd2, outp);
}